// Round 1
// baseline (3481.941 us; speedup 1.0000x reference)
//
#include <hip/hip_runtime.h>
#include <stdint.h>

#define NN 50000      // nodes
#define NE 800000     // edges
#define DD 256        // node feature dim
#define EM 512        // MLP hidden dim
#define NL 4          // layers
#define EPS 1e-5f

typedef unsigned short u16;
typedef __attribute__((ext_vector_type(4))) unsigned short u16x4;
typedef __attribute__((ext_vector_type(8))) short s16x8;
typedef __attribute__((ext_vector_type(8))) float f32x8;
typedef __attribute__((ext_vector_type(4))) float f32x4;
typedef __attribute__((ext_vector_type(8))) __bf16 bf16x8;

union Frag { s16x8 s; bf16x8 b; };

__device__ __forceinline__ float bf2f(u16 h) {
  unsigned u = ((unsigned)h) << 16;
  return __builtin_bit_cast(float, u);
}
__device__ __forceinline__ u16 f2bf(float f) {
  unsigned u = __builtin_bit_cast(unsigned, f);
  u = (u + 0x7FFFu + ((u >> 16) & 1u)) >> 16;   // round-nearest-even
  return (u16)u;
}

// async 16B global->LDS (lds base must be wave-uniform; lane i lands at base+16*i)
__device__ __forceinline__ void gload16(const u16* g, u16* l) {
  __builtin_amdgcn_global_load_lds(
      (const __attribute__((address_space(1))) unsigned int*)g,
      (__attribute__((address_space(3))) unsigned int*)l, 16, 0, 0);
}

// ---------------- setup kernels (once per launch) ----------------

__global__ void k_f32_to_bf16(const float* __restrict__ in, u16* __restrict__ out, int n8) {
  int i = blockIdx.x * blockDim.x + threadIdx.x;
  int stride = gridDim.x * blockDim.x;
  for (; i < n8; i += stride) {
    f32x8 v = ((const f32x8*)in)[i];
    s16x8 o;
#pragma unroll
    for (int j = 0; j < 8; j++) o[j] = (short)f2bf(v[j]);
    ((s16x8*)out)[i] = o;
  }
}

// W: (NL, K, Nc) f32 row-major  ->  WT: (NL, Nc, K) bf16 (N-major so GEMM B staging == A staging)
__global__ void k_transpose_w(const float* __restrict__ W, u16* __restrict__ WT, int K, int Nc) {
  int total = NL * K * Nc;
  for (int i = blockIdx.x * blockDim.x + threadIdx.x; i < total; i += gridDim.x * blockDim.x) {
    int l = i / (K * Nc);
    int rem = i - l * (K * Nc);
    int n = rem / K;
    int k = rem - n * K;
    WT[i] = f2bf(W[(size_t)l * K * Nc + (size_t)k * Nc + n]);
  }
}

__global__ void k_deg(const int* __restrict__ dst, int* __restrict__ deg) {
  for (int e = blockIdx.x * blockDim.x + threadIdx.x; e < NE; e += gridDim.x * blockDim.x)
    atomicAdd(&deg[dst[e]], 1);
}

__global__ __launch_bounds__(1024) void k_scan(const int* __restrict__ deg, int* __restrict__ rowptr) {
  __shared__ int part[1024];
  int t = threadIdx.x;
  const int CH = (NN + 1023) / 1024;   // 49
  int base = t * CH;
  int s = 0;
  for (int i = 0; i < CH; i++) { int idx = base + i; if (idx < NN) s += deg[idx]; }
  part[t] = s;
  __syncthreads();
  for (int off = 1; off < 1024; off <<= 1) {
    int v = (t >= off) ? part[t - off] : 0;
    __syncthreads();
    part[t] += v;
    __syncthreads();
  }
  int run = part[t] - s;               // exclusive prefix
  for (int i = 0; i < CH; i++) {
    int idx = base + i;
    if (idx < NN) { rowptr[idx] = run; run += deg[idx]; }
  }
  if (t == 1023) rowptr[NN] = part[1023];
}

__global__ void k_fill(const int* __restrict__ src, const int* __restrict__ dst,
                       const int* __restrict__ rowptr, int* __restrict__ cursor,
                       int* __restrict__ cols) {
  for (int e = blockIdx.x * blockDim.x + threadIdx.x; e < NE; e += gridDim.x * blockDim.x) {
    int d = dst[e];
    int pos = atomicAdd(&cursor[d], 1);
    cols[rowptr[d] + pos] = src[e];
  }
}

// ---------------- per-layer kernels ----------------

// GIN aggregation: one wave per node; agg[i] = h[i] + sum_{j in CSR row i} h[j]  (bf16 in/out, f32 acc)
__global__ __launch_bounds__(256) void k_agg(const u16* __restrict__ h,
                                             const int* __restrict__ rowptr,
                                             const int* __restrict__ cols,
                                             u16* __restrict__ agg) {
  int wid = threadIdx.x >> 6, lane = threadIdx.x & 63;
  int node = blockIdx.x * 4 + wid;     // NN % 4 == 0
  int c0 = lane << 2;                  // 4 ushorts per lane covers 256 cols
  u16x4 v = *(const u16x4*)(h + (size_t)node * DD + c0);
  float a0 = bf2f(v[0]), a1 = bf2f(v[1]), a2 = bf2f(v[2]), a3 = bf2f(v[3]);
  int beg = rowptr[node], end = rowptr[node + 1];
  for (int e = beg; e < end; ++e) {
    int s = cols[e];                   // wave-uniform
    u16x4 w = *(const u16x4*)(h + (size_t)s * DD + c0);
    a0 += bf2f(w[0]); a1 += bf2f(w[1]); a2 += bf2f(w[2]); a3 += bf2f(w[3]);
  }
  u16x4 o; o[0] = f2bf(a0); o[1] = f2bf(a1); o[2] = f2bf(a2); o[3] = f2bf(a3);
  *(u16x4*)(agg + (size_t)node * DD + c0) = o;
}

// C(MxNC) = A(MxK) * BT(NCxK)^T + bias, bf16 in/out, f32 accum (MFMA 16x16x32)
// 128x128 block tile, 4 waves 2x2, K-step 32, linear LDS + global_load_lds.
template <int K, int NC>
__global__ __launch_bounds__(256) void k_gemm(const u16* __restrict__ A,
                                              const u16* __restrict__ BT,
                                              const float* __restrict__ bias,
                                              u16* __restrict__ C, int M) {
  __shared__ u16 Al[128 * 32];
  __shared__ u16 Bl[128 * 32];
  int tid = threadIdx.x;
  int lane = tid & 63, wid = tid >> 6;
  int wm = wid & 1, wn = wid >> 1;
  int brow = blockIdx.x * 128;
  int bcol = blockIdx.y * 128;

  f32x4 zero = {0.f, 0.f, 0.f, 0.f};
  f32x4 acc[4][4];
#pragma unroll
  for (int m = 0; m < 4; m++)
#pragma unroll
    for (int n = 0; n < 4; n++) acc[m][n] = zero;

  // staging: chunk = 16 rows (1KB). wave w stages chunks w and w+4 of both tiles.
  int rinc = lane >> 2;                 // row within chunk
  int cq = (lane & 3) * 8;              // 8-ushort (16B) column quarter
  long ra0 = brow + wid * 16 + rinc;  if (ra0 > M - 1) ra0 = M - 1;
  long ra1 = brow + 64 + wid * 16 + rinc; if (ra1 > M - 1) ra1 = M - 1;
  const u16* gA0 = A + ra0 * K + cq;
  const u16* gA1 = A + ra1 * K + cq;
  const u16* gB0 = BT + (long)(bcol + wid * 16 + rinc) * K + cq;
  const u16* gB1 = BT + (long)(bcol + 64 + wid * 16 + rinc) * K + cq;
  u16* lA0 = &Al[wid * 512];            // wave-uniform bases
  u16* lA1 = &Al[(wid + 4) * 512];
  u16* lB0 = &Bl[wid * 512];
  u16* lB1 = &Bl[(wid + 4) * 512];

  int fr = lane & 15;                   // row/col within 16-tile
  int kk = (lane >> 4) * 8;             // k offset
  const u16* pa = &Al[(wm * 64 + fr) * 32 + kk];
  const u16* pb = &Bl[(wn * 64 + fr) * 32 + kk];

  const int KS = K / 32;
  for (int kt = 0; kt < KS; ++kt) {
    int k0 = kt * 32;
    gload16(gA0 + k0, lA0);
    gload16(gA1 + k0, lA1);
    gload16(gB0 + k0, lB0);
    gload16(gB1 + k0, lB1);
    __syncthreads();                    // drains vmcnt (async LDS stores) + barrier
    Frag a[4], b[4];
#pragma unroll
    for (int m = 0; m < 4; m++) a[m].s = *(const s16x8*)(pa + m * 512);
#pragma unroll
    for (int n = 0; n < 4; n++) b[n].s = *(const s16x8*)(pb + n * 512);
#pragma unroll
    for (int m = 0; m < 4; m++)
#pragma unroll
      for (int n = 0; n < 4; n++)
        acc[m][n] = __builtin_amdgcn_mfma_f32_16x16x32_bf16(a[m].b, b[n].b, acc[m][n], 0, 0, 0);
    __syncthreads();                    // all waves done reading before next stage
  }

  // epilogue: D row=(lane>>4)*4+r, col=lane&15 within each 16x16 frag [m89-verified]
  int colb = bcol + wn * 64;
  float bv[4];
#pragma unroll
  for (int n = 0; n < 4; n++) bv[n] = bias[colb + n * 16 + fr];
  int rb = brow + wm * 64 + ((lane >> 4) << 2);
#pragma unroll
  for (int m = 0; m < 4; m++) {
#pragma unroll
    for (int r = 0; r < 4; r++) {
      int row = rb + m * 16 + r;
      if (row < M) {
        size_t base = (size_t)row * NC + colb + fr;
#pragma unroll
        for (int n = 0; n < 4; n++)
          C[base + n * 16] = f2bf(acc[m][n][r] + bv[n]);
      }
    }
  }
}

// column sums / sumsq over M rows (for train-mode BN batch stats)
template <int NC>
__global__ __launch_bounds__(256) void k_colstats(const u16* __restrict__ Z, float* __restrict__ stats) {
  const int G = NC / 8;                 // 8-col groups
  const int RPB = 256 / G;              // rows per block-iter
  int tid = threadIdx.x;
  int g = tid % G, rsub = tid / G;
  float s[8], q[8];
#pragma unroll
  for (int j = 0; j < 8; j++) { s[j] = 0.f; q[j] = 0.f; }
  for (int r = blockIdx.x * RPB + rsub; r < NN; r += gridDim.x * RPB) {
    s16x8 v = *(const s16x8*)(Z + (size_t)r * NC + g * 8);
#pragma unroll
    for (int j = 0; j < 8; j++) {
      float f = bf2f((u16)v[j]);
      s[j] += f; q[j] += f * f;
    }
  }
#pragma unroll
  for (int j = 0; j < 8; j++) {
    atomicAdd(&stats[g * 8 + j], s[j]);
    atomicAdd(&stats[NC + g * 8 + j], q[j]);
  }
}

__global__ void k_finalize(const float* __restrict__ stats, const float* __restrict__ gamma,
                           const float* __restrict__ beta, float* __restrict__ ss, int NC) {
  int c = blockIdx.x * blockDim.x + threadIdx.x;
  if (c < NC) {
    float mean = stats[c] * (1.0f / NN);
    float var = stats[NC + c] * (1.0f / NN) - mean * mean;
    float sc = gamma[c] * rsqrtf(var + EPS);
    ss[c] = sc;
    ss[NC + c] = beta[c] - mean * sc;
  }
}

template <int NC, bool RELU>
__global__ void k_bn_bf16(const u16* Z, const float* __restrict__ ss, u16* out, int n8) {
  int i = blockIdx.x * blockDim.x + threadIdx.x;
  int stride = gridDim.x * blockDim.x;
  for (; i < n8; i += stride) {
    int cb = (i * 8) & (NC - 1);
    s16x8 v = *(const s16x8*)(Z + (size_t)i * 8);
    s16x8 o;
#pragma unroll
    for (int j = 0; j < 8; j++) {
      float f = bf2f((u16)v[j]) * ss[cb + j] + ss[NC + cb + j];
      if (RELU) f = fmaxf(f, 0.f);
      o[j] = (short)f2bf(f);
    }
    *(s16x8*)(out + (size_t)i * 8) = o;
  }
}

template <int NC>
__global__ void k_bn_f32(const u16* __restrict__ Z, const float* __restrict__ ss,
                         float* __restrict__ out, int n8) {
  int i = blockIdx.x * blockDim.x + threadIdx.x;
  int stride = gridDim.x * blockDim.x;
  for (; i < n8; i += stride) {
    int cb = (i * 8) & (NC - 1);
    s16x8 v = *(const s16x8*)(Z + (size_t)i * 8);
    f32x8 o;
#pragma unroll
    for (int j = 0; j < 8; j++)
      o[j] = bf2f((u16)v[j]) * ss[cb + j] + ss[NC + cb + j];   // last layer: no ReLU
    *(f32x8*)(out + (size_t)i * 8) = o;
  }
}

// ---------------- host ----------------

extern "C" void kernel_launch(void* const* d_in, const int* in_sizes, int n_in,
                              void* d_out, int out_size, void* d_ws, size_t ws_size,
                              hipStream_t stream) {
  const float* x  = (const float*)d_in[0];
  const int* ei   = (const int*)d_in[1];
  const int* esrc = ei;
  const int* edst = ei + NE;
  const float* W1 = (const float*)d_in[2];
  const float* b1 = (const float*)d_in[3];
  const float* g1 = (const float*)d_in[4];
  const float* be1= (const float*)d_in[5];
  const float* W2 = (const float*)d_in[6];
  const float* b2 = (const float*)d_in[7];
  const float* g2 = (const float*)d_in[8];
  const float* be2= (const float*)d_in[9];
  float* out = (float*)d_out;

  char* w = (char*)d_ws;
  auto alloc = [&](size_t bytes) {
    char* p = w;
    w += (bytes + 255) & ~(size_t)255;
    return p;
  };
  u16* hA   = (u16*)alloc((size_t)NN * DD * 2);
  u16* hB   = (u16*)alloc((size_t)NN * DD * 2);
  u16* AG   = (u16*)alloc((size_t)NN * DD * 2);   // agg, then reused for z2
  u16* Z1   = (u16*)alloc((size_t)NN * EM * 2);
  u16* W1T  = (u16*)alloc((size_t)NL * EM * DD * 2);
  u16* W2T  = (u16*)alloc((size_t)NL * DD * EM * 2);
  int* deg    = (int*)alloc((size_t)NN * 4);
  int* rowptr = (int*)alloc((size_t)(NN + 1) * 4);
  int* cursor = (int*)alloc((size_t)NN * 4);
  int* cols   = (int*)alloc((size_t)NE * 4);
  float* stats = (float*)alloc(2 * EM * 4);
  float* ss    = (float*)alloc(2 * EM * 4);

  // ---- one-time prep ----
  hipMemsetAsync(deg, 0, (size_t)NN * 4, stream);
  hipMemsetAsync(cursor, 0, (size_t)NN * 4, stream);
  k_deg<<<2048, 256, 0, stream>>>(edst, deg);
  k_scan<<<1, 1024, 0, stream>>>(deg, rowptr);
  k_fill<<<2048, 256, 0, stream>>>(esrc, edst, rowptr, cursor, cols);
  k_f32_to_bf16<<<2048, 256, 0, stream>>>(x, hA, NN * DD / 8);
  k_transpose_w<<<2048, 256, 0, stream>>>(W1, W1T, DD, EM);
  k_transpose_w<<<2048, 256, 0, stream>>>(W2, W2T, EM, DD);

  u16* hcur = hA;
  u16* hnext = hB;
  for (int l = 0; l < NL; ++l) {
    k_agg<<<NN / 4, 256, 0, stream>>>(hcur, rowptr, cols, AG);

    k_gemm<DD, EM><<<dim3((NN + 127) / 128, EM / 128), 256, 0, stream>>>(
        AG, W1T + (size_t)l * EM * DD, b1 + (size_t)l * EM, Z1, NN);
    hipMemsetAsync(stats, 0, 2 * EM * 4, stream);
    k_colstats<EM><<<256, 256, 0, stream>>>(Z1, stats);
    k_finalize<<<(EM + 255) / 256, 256, 0, stream>>>(stats, g1 + (size_t)l * EM, be1 + (size_t)l * EM, ss, EM);
    k_bn_bf16<EM, true><<<2048, 256, 0, stream>>>(Z1, ss, Z1, NN * EM / 8);

    k_gemm<EM, DD><<<dim3((NN + 127) / 128, DD / 128), 256, 0, stream>>>(
        Z1, W2T + (size_t)l * DD * EM, b2 + (size_t)l * DD, AG, NN);
    hipMemsetAsync(stats, 0, 2 * DD * 4, stream);
    k_colstats<DD><<<256, 256, 0, stream>>>(AG, stats);
    k_finalize<<<(DD + 255) / 256, 256, 0, stream>>>(stats, g2 + (size_t)l * DD, be2 + (size_t)l * DD, ss, DD);

    if (l < NL - 1) {
      k_bn_bf16<DD, true><<<2048, 256, 0, stream>>>(AG, ss, hnext, NN * DD / 8);
      u16* t = hcur; hcur = hnext; hnext = t;
    } else {
      k_bn_f32<DD><<<2048, 256, 0, stream>>>(AG, ss, out, NN * DD / 8);
    }
  }
}

// Round 4
// 1441.216 us; speedup vs baseline: 2.4160x; 2.4160x over previous
//
#include <hip/hip_runtime.h>
#include <stdint.h>

#define NN 50000      // nodes
#define NE 800000     // edges
#define DD 256        // node feature dim
#define EM 512        // MLP hidden dim
#define NL 4          // layers
#define EPS 1e-5f

typedef unsigned short u16;
typedef __attribute__((ext_vector_type(4))) unsigned short u16x4;
typedef __attribute__((ext_vector_type(8))) short s16x8;
typedef __attribute__((ext_vector_type(8))) float f32x8;
typedef __attribute__((ext_vector_type(4))) float f32x4;
typedef __attribute__((ext_vector_type(8))) __bf16 bf16x8;

union Frag { s16x8 s; bf16x8 b; };

__device__ __forceinline__ float bf2f(u16 h) {
  unsigned u = ((unsigned)h) << 16;
  return __builtin_bit_cast(float, u);
}
__device__ __forceinline__ u16 f2bf(float f) {
  unsigned u = __builtin_bit_cast(unsigned, f);
  u = (u + 0x7FFFu + ((u >> 16) & 1u)) >> 16;   // round-nearest-even
  return (u16)u;
}
// split f32 into bf16 hi + bf16 lo with hi+lo ~= f (error ~2^-18 rel)
__device__ __forceinline__ void bfsplit(float f, u16& hi, u16& lo) {
  hi = f2bf(f);
  lo = f2bf(f - bf2f(hi));
}

// async 16B global->LDS (lds base must be wave-uniform; lane i lands at base+16*i)
__device__ __forceinline__ void gload16(const u16* g, u16* l) {
  __builtin_amdgcn_global_load_lds(
      (const __attribute__((address_space(1))) unsigned int*)g,
      (__attribute__((address_space(3))) unsigned int*)l, 16, 0, 0);
}

// ---------------- setup kernels (once per launch) ----------------

// W: (NL, K, Nc) f32 row-major -> WT hi/lo: (NL, Nc, K) bf16 split (N-major)
__global__ void k_prep_w(const float* __restrict__ W, u16* __restrict__ WThi,
                         u16* __restrict__ WTlo, int K, int Nc) {
  int total = NL * K * Nc;
  for (int i = blockIdx.x * blockDim.x + threadIdx.x; i < total; i += gridDim.x * blockDim.x) {
    int l = i / (K * Nc);
    int rem = i - l * (K * Nc);
    int n = rem / K;
    int k = rem - n * K;
    float v = W[(size_t)l * K * Nc + (size_t)k * Nc + n];
    u16 hi, lo; bfsplit(v, hi, lo);
    WThi[i] = hi; WTlo[i] = lo;
  }
}

__global__ void k_deg(const int* __restrict__ dst, int* __restrict__ deg) {
  for (int e = blockIdx.x * blockDim.x + threadIdx.x; e < NE; e += gridDim.x * blockDim.x)
    atomicAdd(&deg[dst[e]], 1);
}

__global__ __launch_bounds__(1024) void k_scan(const int* __restrict__ deg, int* __restrict__ rowptr) {
  __shared__ int part[1024];
  int t = threadIdx.x;
  const int CH = (NN + 1023) / 1024;   // 49
  int base = t * CH;
  int s = 0;
  for (int i = 0; i < CH; i++) { int idx = base + i; if (idx < NN) s += deg[idx]; }
  part[t] = s;
  __syncthreads();
  for (int off = 1; off < 1024; off <<= 1) {
    int v = (t >= off) ? part[t - off] : 0;
    __syncthreads();
    part[t] += v;
    __syncthreads();
  }
  int run = part[t] - s;               // exclusive prefix
  for (int i = 0; i < CH; i++) {
    int idx = base + i;
    if (idx < NN) { rowptr[idx] = run; run += deg[idx]; }
  }
  if (t == 1023) rowptr[NN] = part[1023];
}

__global__ void k_fill(const int* __restrict__ src, const int* __restrict__ dst,
                       const int* __restrict__ rowptr, int* __restrict__ cursor,
                       int* __restrict__ cols) {
  for (int e = blockIdx.x * blockDim.x + threadIdx.x; e < NE; e += gridDim.x * blockDim.x) {
    int d = dst[e];
    int pos = atomicAdd(&cursor[d], 1);
    cols[rowptr[d] + pos] = src[e];
  }
}

// ---------------- per-layer kernels ----------------

// GIN aggregation with (optionally) fused BN2+ReLU of the previous layer:
//   h_j = FUSED ? relu(src_j*sc+sh) : src_j ;  agg_i = h_i + sum_{j->i} h_j
// one wave per node, f32 in, split-bf16 out.
template <bool FUSED>
__global__ __launch_bounds__(256) void k_agg(const float* __restrict__ src,
                                             const float* __restrict__ ss,
                                             const int* __restrict__ rowptr,
                                             const int* __restrict__ cols,
                                             u16* __restrict__ Ahi,
                                             u16* __restrict__ Alo) {
  int wid = threadIdx.x >> 6, lane = threadIdx.x & 63;
  int node = blockIdx.x * 4 + wid;     // NN % 4 == 0
  int c0 = lane << 2;                  // 4 floats per lane covers 256 cols
  f32x4 sc, sh;
  if (FUSED) {
    sc = *(const f32x4*)(ss + c0);
    sh = *(const f32x4*)(ss + DD + c0);
  }
  f32x4 a = *(const f32x4*)(src + (size_t)node * DD + c0);
  if (FUSED) {
#pragma unroll
    for (int j = 0; j < 4; j++) a[j] = fmaxf(a[j] * sc[j] + sh[j], 0.f);
  }
  int beg = rowptr[node], end = rowptr[node + 1];
  for (int e = beg; e < end; ++e) {
    int s = cols[e];                   // wave-uniform
    f32x4 w = *(const f32x4*)(src + (size_t)s * DD + c0);
    if (FUSED) {
#pragma unroll
      for (int j = 0; j < 4; j++) w[j] = fmaxf(w[j] * sc[j] + sh[j], 0.f);
    }
    a += w;
  }
  u16x4 oh, ol;
#pragma unroll
  for (int j = 0; j < 4; j++) { u16 hi, lo; bfsplit(a[j], hi, lo); oh[j] = hi; ol[j] = lo; }
  *(u16x4*)(Ahi + (size_t)node * DD + c0) = oh;
  *(u16x4*)(Alo + (size_t)node * DD + c0) = ol;
}

// C(MxNC) = A(MxK) * W(KxNC) + bias via NSEG bf16 MFMA segments:
//   NSEG==3: Ahi*Whi + Alo*Whi + Ahi*Wlo     (A given as split pair)
//   NSEG==2: A*Whi + A*Wlo                   (A plain bf16; pass Alo==Ahi)
// Z output: bf16 (OUT_BF16) or f32. Per-column batch sums/sumsq -> stats[2*NC].
// 128x128 block tile, 4 waves 2x2, K-step 32, linear LDS + global_load_lds.
template <int K, int NC, bool OUT_BF16, int NSEG>
__global__ __launch_bounds__(256) void k_gemm(const u16* __restrict__ Ahi,
                                              const u16* __restrict__ Alo,
                                              const u16* __restrict__ WThi,
                                              const u16* __restrict__ WTlo,
                                              const float* __restrict__ bias,
                                              void* __restrict__ Zout,
                                              float* __restrict__ stats, int M) {
  __shared__ u16 Al[128 * 32];
  __shared__ u16 Bl[128 * 32];
  __shared__ float sblk[256];          // [0..128) col sums, [128..256) col sumsq
  int tid = threadIdx.x;
  sblk[tid] = 0.f;                     // 256 threads cover 256 slots
  int lane = tid & 63, wid = tid >> 6;
  int wm = wid & 1, wn = wid >> 1;
  int brow = blockIdx.x * 128;
  int bcol = blockIdx.y * 128;

  f32x4 zero = {0.f, 0.f, 0.f, 0.f};
  f32x4 acc[4][4];
#pragma unroll
  for (int m = 0; m < 4; m++)
#pragma unroll
    for (int n = 0; n < 4; n++) acc[m][n] = zero;

  // staging: chunk = 16 rows (1KB). wave w stages chunks w and w+4 of both tiles.
  int rinc = lane >> 2;                 // row within chunk
  int cq = (lane & 3) * 8;              // 8-ushort (16B) column quarter
  long ra0 = brow + wid * 16 + rinc;  if (ra0 > M - 1) ra0 = M - 1;
  long ra1 = brow + 64 + wid * 16 + rinc; if (ra1 > M - 1) ra1 = M - 1;
  long rb0 = bcol + wid * 16 + rinc;
  long rb1 = bcol + 64 + wid * 16 + rinc;
  u16* lA0 = &Al[wid * 512];            // wave-uniform bases
  u16* lA1 = &Al[(wid + 4) * 512];
  u16* lB0 = &Bl[wid * 512];
  u16* lB1 = &Bl[(wid + 4) * 512];

  int fr = lane & 15;                   // row/col within 16-tile
  int kk = (lane >> 4) * 8;             // k offset
  const u16* pa = &Al[(wm * 64 + fr) * 32 + kk];
  const u16* pb = &Bl[(wn * 64 + fr) * 32 + kk];

  const int KS = K / 32;
#pragma unroll 1
  for (int seg = 0; seg < NSEG; ++seg) {
    const u16* Ab = (NSEG == 3 && seg == 1) ? Alo : Ahi;
    const u16* Bb = (seg == NSEG - 1) ? WTlo : WThi;
    const u16* gA0 = Ab + ra0 * K + cq;
    const u16* gA1 = Ab + ra1 * K + cq;
    const u16* gB0 = Bb + rb0 * K + cq;
    const u16* gB1 = Bb + rb1 * K + cq;
    for (int kt = 0; kt < KS; ++kt) {
      int k0 = kt * 32;
      gload16(gA0 + k0, lA0);
      gload16(gA1 + k0, lA1);
      gload16(gB0 + k0, lB0);
      gload16(gB1 + k0, lB1);
      __syncthreads();                  // drains vmcnt (async LDS stores) + barrier
      Frag a[4], b[4];
#pragma unroll
      for (int m = 0; m < 4; m++) a[m].s = *(const s16x8*)(pa + m * 512);
#pragma unroll
      for (int n = 0; n < 4; n++) b[n].s = *(const s16x8*)(pb + n * 512);
#pragma unroll
      for (int m = 0; m < 4; m++)
#pragma unroll
        for (int n = 0; n < 4; n++)
          acc[m][n] = __builtin_amdgcn_mfma_f32_16x16x32_bf16(a[m].b, b[n].b, acc[m][n], 0, 0, 0);
      __syncthreads();                  // all waves done reading before next stage
    }
  }

  // epilogue: D row=(lane>>4)*4+r, col=lane&15 within each 16x16 frag [m89-verified]
  int colb = bcol + wn * 64;
  float bv[4];
#pragma unroll
  for (int n = 0; n < 4; n++) bv[n] = bias[colb + n * 16 + fr];
  int rb = brow + wm * 64 + ((lane >> 4) << 2);
  float sn[4] = {0.f, 0.f, 0.f, 0.f}, qn[4] = {0.f, 0.f, 0.f, 0.f};
#pragma unroll
  for (int m = 0; m < 4; m++) {
#pragma unroll
    for (int r = 0; r < 4; r++) {
      int row = rb + m * 16 + r;
      if (row < M) {
        size_t base = (size_t)row * NC + colb + fr;
#pragma unroll
        for (int n = 0; n < 4; n++) {
          float z = acc[m][n][r] + bv[n];
          if (OUT_BF16) ((u16*)Zout)[base + n * 16] = f2bf(z);
          else          ((float*)Zout)[base + n * 16] = z;
          sn[n] += z; qn[n] += z * z;
        }
      }
    }
  }
  // reduce across the 4 row-groups of the wave (lanes differing in bits 4,5)
#pragma unroll
  for (int n = 0; n < 4; n++) {
    sn[n] += __shfl_xor(sn[n], 16); sn[n] += __shfl_xor(sn[n], 32);
    qn[n] += __shfl_xor(qn[n], 16); qn[n] += __shfl_xor(qn[n], 32);
  }
  if (lane < 16) {
#pragma unroll
    for (int n = 0; n < 4; n++) {
      atomicAdd(&sblk[wn * 64 + n * 16 + lane], sn[n]);
      atomicAdd(&sblk[128 + wn * 64 + n * 16 + lane], qn[n]);
    }
  }
  __syncthreads();
  if (tid < 128) atomicAdd(&stats[bcol + tid], sblk[tid]);
  else           atomicAdd(&stats[NC + bcol + (tid - 128)], sblk[tid]);
}

__global__ void k_finalize(const float* __restrict__ stats, const float* __restrict__ gamma,
                           const float* __restrict__ beta, float* __restrict__ ss, int NC) {
  int c = blockIdx.x * blockDim.x + threadIdx.x;
  if (c < NC) {
    float mean = stats[c] * (1.0f / NN);
    float var = stats[NC + c] * (1.0f / NN) - mean * mean;
    float sc = gamma[c] * rsqrtf(var + EPS);
    ss[c] = sc;
    ss[NC + c] = beta[c] - mean * sc;
  }
}

// BN1 + ReLU on bf16 Z1 -> plain bf16 A2 (GEMM2 input)
template <int NC>
__global__ void k_bn_a2(const u16* __restrict__ Z, const float* __restrict__ ss,
                        u16* __restrict__ A2, int n8) {
  int i = blockIdx.x * blockDim.x + threadIdx.x;
  int stride = gridDim.x * blockDim.x;
  for (; i < n8; i += stride) {
    int c = (i * 8) & (NC - 1);
    s16x8 v = *(const s16x8*)(Z + (size_t)i * 8);
    s16x8 o;
#pragma unroll
    for (int j = 0; j < 8; j++) {
      float f = fmaxf(bf2f((u16)v[j]) * ss[c + j] + ss[NC + c + j], 0.f);
      o[j] = (short)f2bf(f);
    }
    *(s16x8*)(A2 + (size_t)i * 8) = o;
  }
}

// final-layer BN2 (no ReLU) on f32 Z2 -> f32 d_out
template <int NC>
__global__ void k_bn_out(const float* __restrict__ Z, const float* __restrict__ ss,
                         float* __restrict__ out, int n4) {
  int i = blockIdx.x * blockDim.x + threadIdx.x;
  int stride = gridDim.x * blockDim.x;
  for (; i < n4; i += stride) {
    int c = (i * 4) & (NC - 1);
    f32x4 v = *(const f32x4*)(Z + (size_t)i * 4);
    f32x4 o;
#pragma unroll
    for (int j = 0; j < 4; j++) o[j] = v[j] * ss[c + j] + ss[NC + c + j];
    *(f32x4*)(out + (size_t)i * 4) = o;
  }
}

// ---------------- host ----------------

extern "C" void kernel_launch(void* const* d_in, const int* in_sizes, int n_in,
                              void* d_out, int out_size, void* d_ws, size_t ws_size,
                              hipStream_t stream) {
  const float* x  = (const float*)d_in[0];
  const int* ei   = (const int*)d_in[1];
  const int* esrc = ei;
  const int* edst = ei + NE;
  const float* W1 = (const float*)d_in[2];
  const float* b1 = (const float*)d_in[3];
  const float* g1 = (const float*)d_in[4];
  const float* be1= (const float*)d_in[5];
  const float* W2 = (const float*)d_in[6];
  const float* b2 = (const float*)d_in[7];
  const float* g2 = (const float*)d_in[8];
  const float* be2= (const float*)d_in[9];
  float* out = (float*)d_out;

  char* w = (char*)d_ws;
  auto alloc = [&](size_t bytes) {
    char* p = w;
    w += (bytes + 255) & ~(size_t)255;
    return p;
  };
  // Two 51.2MB ping-pong regions (total ws ~107MB; round-1-proven budget was 134MB):
  //   R0: Z1 (bf16 [NN][512]) then Z2 (f32 [NN][256])
  //   R1: A1 split pair (bf16 [NN][256] x2) then A2 (bf16 [NN][512])
  char* R0 = alloc((size_t)NN * EM * 2);
  char* R1 = alloc((size_t)NN * EM * 2);
  u16* W1hi = (u16*)alloc((size_t)NL * EM * DD * 2);
  u16* W1lo = (u16*)alloc((size_t)NL * EM * DD * 2);
  u16* W2hi = (u16*)alloc((size_t)NL * DD * EM * 2);
  u16* W2lo = (u16*)alloc((size_t)NL * DD * EM * 2);
  int* deg    = (int*)alloc((size_t)NN * 4);
  int* rowptr = (int*)alloc((size_t)(NN + 1) * 4);
  int* cursor = (int*)alloc((size_t)NN * 4);
  int* cols   = (int*)alloc((size_t)NE * 4);
  float* stats1 = (float*)alloc(2 * EM * 4);
  float* stats2 = (float*)alloc(2 * DD * 4);
  float* ss1    = (float*)alloc(2 * EM * 4);
  float* ss2    = (float*)alloc(2 * DD * 4);

  u16*   Z1   = (u16*)R0;
  float* Z2   = (float*)R0;
  u16*   A1hi = (u16*)R1;
  u16*   A1lo = (u16*)R1 + (size_t)NN * DD;
  u16*   A2   = (u16*)R1;

  // ---- one-time prep ----
  hipMemsetAsync(deg, 0, (size_t)NN * 4, stream);
  hipMemsetAsync(cursor, 0, (size_t)NN * 4, stream);
  k_deg<<<2048, 256, 0, stream>>>(edst, deg);
  k_scan<<<1, 1024, 0, stream>>>(deg, rowptr);
  k_fill<<<2048, 256, 0, stream>>>(esrc, edst, rowptr, cursor, cols);
  k_prep_w<<<2048, 256, 0, stream>>>(W1, W1hi, W1lo, DD, EM);
  k_prep_w<<<2048, 256, 0, stream>>>(W2, W2hi, W2lo, EM, DD);

  for (int l = 0; l < NL; ++l) {
    // aggregation (BN2+ReLU of previous layer fused into the gather for l>0)
    if (l == 0)
      k_agg<false><<<NN / 4, 256, 0, stream>>>(x, nullptr, rowptr, cols, A1hi, A1lo);
    else
      k_agg<true><<<NN / 4, 256, 0, stream>>>(Z2, ss2, rowptr, cols, A1hi, A1lo);

    hipMemsetAsync(stats1, 0, 2 * EM * 4, stream);
    k_gemm<DD, EM, true, 3><<<dim3((NN + 127) / 128, EM / 128), 256, 0, stream>>>(
        A1hi, A1lo, W1hi + (size_t)l * EM * DD, W1lo + (size_t)l * EM * DD,
        b1 + (size_t)l * EM, Z1, stats1, NN);
    k_finalize<<<2, 256, 0, stream>>>(stats1, g1 + (size_t)l * EM, be1 + (size_t)l * EM, ss1, EM);
    k_bn_a2<EM><<<2048, 256, 0, stream>>>(Z1, ss1, A2, NN * EM / 8);

    hipMemsetAsync(stats2, 0, 2 * DD * 4, stream);
    k_gemm<EM, DD, false, 2><<<dim3((NN + 127) / 128, DD / 128), 256, 0, stream>>>(
        A2, A2, W2hi + (size_t)l * DD * EM, W2lo + (size_t)l * DD * EM,
        b2 + (size_t)l * DD, Z2, stats2, NN);
    k_finalize<<<1, 256, 0, stream>>>(stats2, g2 + (size_t)l * DD, be2 + (size_t)l * DD, ss2, DD);
  }
  k_bn_out<DD><<<2048, 256, 0, stream>>>(Z2, ss2, out, NN * DD / 4);
}

// Round 5
// 1326.300 us; speedup vs baseline: 2.6253x; 1.0866x over previous
//
#include <hip/hip_runtime.h>
#include <stdint.h>

#define NN 50000      // nodes
#define NE 800000     // edges
#define DD 256        // node feature dim
#define EM 512        // MLP hidden dim
#define NL 4          // layers
#define EPS 1e-5f

typedef unsigned short u16;
typedef __attribute__((ext_vector_type(4))) unsigned short u16x4;
typedef __attribute__((ext_vector_type(8))) short s16x8;
typedef __attribute__((ext_vector_type(8))) float f32x8;
typedef __attribute__((ext_vector_type(4))) float f32x4;
typedef __attribute__((ext_vector_type(8))) __bf16 bf16x8;

union Frag { s16x8 s; bf16x8 b; };

__device__ __forceinline__ float bf2f(u16 h) {
  unsigned u = ((unsigned)h) << 16;
  return __builtin_bit_cast(float, u);
}
__device__ __forceinline__ u16 f2bf(float f) {
  unsigned u = __builtin_bit_cast(unsigned, f);
  u = (u + 0x7FFFu + ((u >> 16) & 1u)) >> 16;   // round-nearest-even
  return (u16)u;
}
// split f32 into bf16 hi + bf16 lo with hi+lo ~= f (error ~2^-18 rel)
__device__ __forceinline__ void bfsplit(float f, u16& hi, u16& lo) {
  hi = f2bf(f);
  lo = f2bf(f - bf2f(hi));
}

// async 16B global->LDS (lds base must be wave-uniform; lane i lands at base+16*i)
__device__ __forceinline__ void gload16(const u16* g, u16* l) {
  __builtin_amdgcn_global_load_lds(
      (const __attribute__((address_space(1))) unsigned int*)g,
      (__attribute__((address_space(3))) unsigned int*)l, 16, 0, 0);
}

// ---------------- setup kernels (once per launch) ----------------

__global__ void k_f32_to_bf16(const float* __restrict__ in, u16* __restrict__ out, int n8) {
  int i = blockIdx.x * blockDim.x + threadIdx.x;
  int stride = gridDim.x * blockDim.x;
  for (; i < n8; i += stride) {
    f32x8 v = ((const f32x8*)in)[i];
    s16x8 o;
#pragma unroll
    for (int j = 0; j < 8; j++) o[j] = (short)f2bf(v[j]);
    ((s16x8*)out)[i] = o;
  }
}

// W: (NL, K, Nc) f32 row-major -> WT hi/lo: (NL, Nc, K) bf16 split (N-major)
__global__ void k_prep_w(const float* __restrict__ W, u16* __restrict__ WThi,
                         u16* __restrict__ WTlo, int K, int Nc) {
  int total = NL * K * Nc;
  for (int i = blockIdx.x * blockDim.x + threadIdx.x; i < total; i += gridDim.x * blockDim.x) {
    int l = i / (K * Nc);
    int rem = i - l * (K * Nc);
    int n = rem / K;
    int k = rem - n * K;
    float v = W[(size_t)l * K * Nc + (size_t)k * Nc + n];
    u16 hi, lo; bfsplit(v, hi, lo);
    WThi[i] = hi; WTlo[i] = lo;
  }
}

__global__ void k_deg(const int* __restrict__ dst, int* __restrict__ deg) {
  for (int e = blockIdx.x * blockDim.x + threadIdx.x; e < NE; e += gridDim.x * blockDim.x)
    atomicAdd(&deg[dst[e]], 1);
}

__global__ __launch_bounds__(1024) void k_scan(const int* __restrict__ deg, int* __restrict__ rowptr) {
  __shared__ int part[1024];
  int t = threadIdx.x;
  const int CH = (NN + 1023) / 1024;   // 49
  int base = t * CH;
  int s = 0;
  for (int i = 0; i < CH; i++) { int idx = base + i; if (idx < NN) s += deg[idx]; }
  part[t] = s;
  __syncthreads();
  for (int off = 1; off < 1024; off <<= 1) {
    int v = (t >= off) ? part[t - off] : 0;
    __syncthreads();
    part[t] += v;
    __syncthreads();
  }
  int run = part[t] - s;               // exclusive prefix
  for (int i = 0; i < CH; i++) {
    int idx = base + i;
    if (idx < NN) { rowptr[idx] = run; run += deg[idx]; }
  }
  if (t == 1023) rowptr[NN] = part[1023];
}

__global__ void k_fill(const int* __restrict__ src, const int* __restrict__ dst,
                       const int* __restrict__ rowptr, int* __restrict__ cursor,
                       int* __restrict__ cols) {
  for (int e = blockIdx.x * blockDim.x + threadIdx.x; e < NE; e += gridDim.x * blockDim.x) {
    int d = dst[e];
    int pos = atomicAdd(&cursor[d], 1);
    cols[rowptr[d] + pos] = src[e];
  }
}

// ---------------- per-layer kernels ----------------

// GIN aggregation from a bf16 source (512B rows) with optionally fused BN2+ReLU:
//   h_j = FUSED ? relu(src_j*sc+sh) : src_j ;  agg_i = h_i + sum_{j->i} h_j
// one wave per node, bf16 in, split-bf16 out, f32 accumulate.
template <bool FUSED>
__global__ __launch_bounds__(256) void k_agg(const u16* __restrict__ src,
                                             const float* __restrict__ ss,
                                             const int* __restrict__ rowptr,
                                             const int* __restrict__ cols,
                                             u16* __restrict__ Ahi,
                                             u16* __restrict__ Alo) {
  int wid = threadIdx.x >> 6, lane = threadIdx.x & 63;
  int node = blockIdx.x * 4 + wid;     // NN % 4 == 0
  int c0 = lane << 2;                  // 4 cols per lane covers 256 cols
  f32x4 sc, sh;
  if (FUSED) {
    sc = *(const f32x4*)(ss + c0);
    sh = *(const f32x4*)(ss + DD + c0);
  }
  u16x4 v = *(const u16x4*)(src + (size_t)node * DD + c0);
  f32x4 a;
#pragma unroll
  for (int j = 0; j < 4; j++) {
    float f = bf2f(v[j]);
    a[j] = FUSED ? fmaxf(f * sc[j] + sh[j], 0.f) : f;
  }
  int beg = rowptr[node], end = rowptr[node + 1];
  for (int e = beg; e < end; ++e) {
    int s = cols[e];                   // wave-uniform
    u16x4 w = *(const u16x4*)(src + (size_t)s * DD + c0);
#pragma unroll
    for (int j = 0; j < 4; j++) {
      float f = bf2f(w[j]);
      a[j] += FUSED ? fmaxf(f * sc[j] + sh[j], 0.f) : f;
    }
  }
  u16x4 oh, ol;
#pragma unroll
  for (int j = 0; j < 4; j++) { u16 hi, lo; bfsplit(a[j], hi, lo); oh[j] = hi; ol[j] = lo; }
  *(u16x4*)(Ahi + (size_t)node * DD + c0) = oh;
  *(u16x4*)(Alo + (size_t)node * DD + c0) = ol;
}

// C(MxNC) = A(MxK) * W(KxNC) + bias via NSEG bf16 MFMA segments:
//   NSEG==3: Ahi*Whi + Alo*Whi + Ahi*Wlo     (A given as split pair)
//   NSEG==2: A*Whi + A*Wlo                   (A plain bf16; pass Alo==Ahi)
// Z output: bf16 (OUT_BF16) or f32. Per-column batch sums/sumsq -> stats[2*NC].
// 128x128 block tile, 4 waves 2x2, K-step 32, linear LDS + global_load_lds.
template <int K, int NC, bool OUT_BF16, int NSEG>
__global__ __launch_bounds__(256) void k_gemm(const u16* __restrict__ Ahi,
                                              const u16* __restrict__ Alo,
                                              const u16* __restrict__ WThi,
                                              const u16* __restrict__ WTlo,
                                              const float* __restrict__ bias,
                                              void* __restrict__ Zout,
                                              float* __restrict__ stats, int M) {
  __shared__ u16 Al[128 * 32];
  __shared__ u16 Bl[128 * 32];
  __shared__ float sblk[256];          // [0..128) col sums, [128..256) col sumsq
  int tid = threadIdx.x;
  sblk[tid] = 0.f;                     // 256 threads cover 256 slots
  int lane = tid & 63, wid = tid >> 6;
  int wm = wid & 1, wn = wid >> 1;
  int brow = blockIdx.x * 128;
  int bcol = blockIdx.y * 128;

  f32x4 zero = {0.f, 0.f, 0.f, 0.f};
  f32x4 acc[4][4];
#pragma unroll
  for (int m = 0; m < 4; m++)
#pragma unroll
    for (int n = 0; n < 4; n++) acc[m][n] = zero;

  // staging: chunk = 16 rows (1KB). wave w stages chunks w and w+4 of both tiles.
  int rinc = lane >> 2;                 // row within chunk
  int cq = (lane & 3) * 8;              // 8-ushort (16B) column quarter
  long ra0 = brow + wid * 16 + rinc;  if (ra0 > M - 1) ra0 = M - 1;
  long ra1 = brow + 64 + wid * 16 + rinc; if (ra1 > M - 1) ra1 = M - 1;
  long rb0 = bcol + wid * 16 + rinc;
  long rb1 = bcol + 64 + wid * 16 + rinc;
  u16* lA0 = &Al[wid * 512];            // wave-uniform bases
  u16* lA1 = &Al[(wid + 4) * 512];
  u16* lB0 = &Bl[wid * 512];
  u16* lB1 = &Bl[(wid + 4) * 512];

  int fr = lane & 15;                   // row/col within 16-tile
  int kk = (lane >> 4) * 8;             // k offset
  const u16* pa = &Al[(wm * 64 + fr) * 32 + kk];
  const u16* pb = &Bl[(wn * 64 + fr) * 32 + kk];

  const int KS = K / 32;
#pragma unroll 1
  for (int seg = 0; seg < NSEG; ++seg) {
    const u16* Ab = (NSEG == 3 && seg == 1) ? Alo : Ahi;
    const u16* Bb = (seg == NSEG - 1) ? WTlo : WThi;
    const u16* gA0 = Ab + ra0 * K + cq;
    const u16* gA1 = Ab + ra1 * K + cq;
    const u16* gB0 = Bb + rb0 * K + cq;
    const u16* gB1 = Bb + rb1 * K + cq;
    for (int kt = 0; kt < KS; ++kt) {
      int k0 = kt * 32;
      gload16(gA0 + k0, lA0);
      gload16(gA1 + k0, lA1);
      gload16(gB0 + k0, lB0);
      gload16(gB1 + k0, lB1);
      __syncthreads();                  // drains vmcnt (async LDS stores) + barrier
      Frag a[4], b[4];
#pragma unroll
      for (int m = 0; m < 4; m++) a[m].s = *(const s16x8*)(pa + m * 512);
#pragma unroll
      for (int n = 0; n < 4; n++) b[n].s = *(const s16x8*)(pb + n * 512);
#pragma unroll
      for (int m = 0; m < 4; m++)
#pragma unroll
        for (int n = 0; n < 4; n++)
          acc[m][n] = __builtin_amdgcn_mfma_f32_16x16x32_bf16(a[m].b, b[n].b, acc[m][n], 0, 0, 0);
      __syncthreads();                  // all waves done reading before next stage
    }
  }

  // epilogue: D row=(lane>>4)*4+r, col=lane&15 within each 16x16 frag [m89-verified]
  int colb = bcol + wn * 64;
  float bv[4];
#pragma unroll
  for (int n = 0; n < 4; n++) bv[n] = bias[colb + n * 16 + fr];
  int rb = brow + wm * 64 + ((lane >> 4) << 2);
  float sn[4] = {0.f, 0.f, 0.f, 0.f}, qn[4] = {0.f, 0.f, 0.f, 0.f};
#pragma unroll
  for (int m = 0; m < 4; m++) {
#pragma unroll
    for (int r = 0; r < 4; r++) {
      int row = rb + m * 16 + r;
      if (row < M) {
        size_t base = (size_t)row * NC + colb + fr;
#pragma unroll
        for (int n = 0; n < 4; n++) {
          float z = acc[m][n][r] + bv[n];
          if (OUT_BF16) ((u16*)Zout)[base + n * 16] = f2bf(z);
          else          ((float*)Zout)[base + n * 16] = z;
          sn[n] += z; qn[n] += z * z;
        }
      }
    }
  }
  // reduce across the 4 row-groups of the wave (lanes differing in bits 4,5)
#pragma unroll
  for (int n = 0; n < 4; n++) {
    sn[n] += __shfl_xor(sn[n], 16); sn[n] += __shfl_xor(sn[n], 32);
    qn[n] += __shfl_xor(qn[n], 16); qn[n] += __shfl_xor(qn[n], 32);
  }
  if (lane < 16) {
#pragma unroll
    for (int n = 0; n < 4; n++) {
      atomicAdd(&sblk[wn * 64 + n * 16 + lane], sn[n]);
      atomicAdd(&sblk[128 + wn * 64 + n * 16 + lane], qn[n]);
    }
  }
  __syncthreads();
  if (tid < 128) atomicAdd(&stats[bcol + tid], sblk[tid]);
  else           atomicAdd(&stats[NC + bcol + (tid - 128)], sblk[tid]);
}

__global__ void k_finalize(const float* __restrict__ stats, const float* __restrict__ gamma,
                           const float* __restrict__ beta, float* __restrict__ ss, int NC) {
  int c = blockIdx.x * blockDim.x + threadIdx.x;
  if (c < NC) {
    float mean = stats[c] * (1.0f / NN);
    float var = stats[NC + c] * (1.0f / NN) - mean * mean;
    float sc = gamma[c] * rsqrtf(var + EPS);
    ss[c] = sc;
    ss[NC + c] = beta[c] - mean * sc;
  }
}

// BN1 + ReLU on bf16 Z1 -> plain bf16 A2 (GEMM2 input)
template <int NC>
__global__ void k_bn_a2(const u16* __restrict__ Z, const float* __restrict__ ss,
                        u16* __restrict__ A2, int n8) {
  int i = blockIdx.x * blockDim.x + threadIdx.x;
  int stride = gridDim.x * blockDim.x;
  for (; i < n8; i += stride) {
    int c = (i * 8) & (NC - 1);
    s16x8 v = *(const s16x8*)(Z + (size_t)i * 8);
    s16x8 o;
#pragma unroll
    for (int j = 0; j < 8; j++) {
      float f = fmaxf(bf2f((u16)v[j]) * ss[c + j] + ss[NC + c + j], 0.f);
      o[j] = (short)f2bf(f);
    }
    *(s16x8*)(A2 + (size_t)i * 8) = o;
  }
}

// final-layer BN2 (no ReLU) on f32 Z2 -> f32 d_out
template <int NC>
__global__ void k_bn_out(const float* __restrict__ Z, const float* __restrict__ ss,
                         float* __restrict__ out, int n4) {
  int i = blockIdx.x * blockDim.x + threadIdx.x;
  int stride = gridDim.x * blockDim.x;
  for (; i < n4; i += stride) {
    int c = (i * 4) & (NC - 1);
    f32x4 v = *(const f32x4*)(Z + (size_t)i * 4);
    f32x4 o;
#pragma unroll
    for (int j = 0; j < 4; j++) o[j] = v[j] * ss[c + j] + ss[NC + c + j];
    *(f32x4*)(out + (size_t)i * 4) = o;
  }
}

// ---------------- host ----------------

extern "C" void kernel_launch(void* const* d_in, const int* in_sizes, int n_in,
                              void* d_out, int out_size, void* d_ws, size_t ws_size,
                              hipStream_t stream) {
  const float* x  = (const float*)d_in[0];
  const int* ei   = (const int*)d_in[1];
  const int* esrc = ei;
  const int* edst = ei + NE;
  const float* W1 = (const float*)d_in[2];
  const float* b1 = (const float*)d_in[3];
  const float* g1 = (const float*)d_in[4];
  const float* be1= (const float*)d_in[5];
  const float* W2 = (const float*)d_in[6];
  const float* b2 = (const float*)d_in[7];
  const float* g2 = (const float*)d_in[8];
  const float* be2= (const float*)d_in[9];
  float* out = (float*)d_out;

  char* w = (char*)d_ws;
  auto alloc = [&](size_t bytes) {
    char* p = w;
    w += (bytes + 255) & ~(size_t)255;
    return p;
  };
  // Two 51.2MB ping-pong regions (total ws ~110MB; round-4-proven budget):
  //   R0: {xb / Z2bf} (bf16 [NN][256], front) | Z1 (bf16 [NN][512], full) | Z2 f32 (last layer, full)
  //   R1: A1 split pair (bf16 [NN][256] x2) then A2 (bf16 [NN][512])
  char* R0 = alloc((size_t)NN * EM * 2);
  char* R1 = alloc((size_t)NN * EM * 2);
  u16* W1hi = (u16*)alloc((size_t)NL * EM * DD * 2);
  u16* W1lo = (u16*)alloc((size_t)NL * EM * DD * 2);
  u16* W2hi = (u16*)alloc((size_t)NL * DD * EM * 2);
  u16* W2lo = (u16*)alloc((size_t)NL * DD * EM * 2);
  int* deg    = (int*)alloc((size_t)NN * 4);
  int* rowptr = (int*)alloc((size_t)(NN + 1) * 4);
  int* cursor = (int*)alloc((size_t)NN * 4);
  int* cols   = (int*)alloc((size_t)NE * 4);
  float* stats1 = (float*)alloc(2 * EM * 4);
  float* stats2 = (float*)alloc(2 * DD * 4);
  float* ss1    = (float*)alloc(2 * EM * 4);
  float* ss2    = (float*)alloc(2 * DD * 4);

  u16*   Hb   = (u16*)R0;              // bf16 [NN][256]: xb for l=0, Z2bf for l>0
  u16*   Z1   = (u16*)R0;
  float* Z2f  = (float*)R0;            // last layer only
  u16*   A1hi = (u16*)R1;
  u16*   A1lo = (u16*)R1 + (size_t)NN * DD;
  u16*   A2   = (u16*)R1;

  // ---- one-time prep ----
  hipMemsetAsync(deg, 0, (size_t)NN * 4, stream);
  hipMemsetAsync(cursor, 0, (size_t)NN * 4, stream);
  k_deg<<<2048, 256, 0, stream>>>(edst, deg);
  k_scan<<<1, 1024, 0, stream>>>(deg, rowptr);
  k_fill<<<2048, 256, 0, stream>>>(esrc, edst, rowptr, cursor, cols);
  k_prep_w<<<2048, 256, 0, stream>>>(W1, W1hi, W1lo, DD, EM);
  k_prep_w<<<2048, 256, 0, stream>>>(W2, W2hi, W2lo, EM, DD);
  k_f32_to_bf16<<<2048, 256, 0, stream>>>(x, Hb, NN * DD / 8);

  for (int l = 0; l < NL; ++l) {
    // aggregation from bf16 rows (BN2+ReLU of previous layer fused for l>0)
    if (l == 0)
      k_agg<false><<<NN / 4, 256, 0, stream>>>(Hb, nullptr, rowptr, cols, A1hi, A1lo);
    else
      k_agg<true><<<NN / 4, 256, 0, stream>>>(Hb, ss2, rowptr, cols, A1hi, A1lo);

    hipMemsetAsync(stats1, 0, 2 * EM * 4, stream);
    k_gemm<DD, EM, true, 3><<<dim3((NN + 127) / 128, EM / 128), 256, 0, stream>>>(
        A1hi, A1lo, W1hi + (size_t)l * EM * DD, W1lo + (size_t)l * EM * DD,
        b1 + (size_t)l * EM, Z1, stats1, NN);
    k_finalize<<<2, 256, 0, stream>>>(stats1, g1 + (size_t)l * EM, be1 + (size_t)l * EM, ss1, EM);
    k_bn_a2<EM><<<2048, 256, 0, stream>>>(Z1, ss1, A2, NN * EM / 8);

    hipMemsetAsync(stats2, 0, 2 * DD * 4, stream);
    if (l < NL - 1) {
      // Z2 stored as plain bf16 (pre-BN) -> next layer's gather source
      k_gemm<EM, DD, true, 2><<<dim3((NN + 127) / 128, DD / 128), 256, 0, stream>>>(
          A2, A2, W2hi + (size_t)l * DD * EM, W2lo + (size_t)l * DD * EM,
          b2 + (size_t)l * DD, Hb, stats2, NN);
    } else {
      k_gemm<EM, DD, false, 2><<<dim3((NN + 127) / 128, DD / 128), 256, 0, stream>>>(
          A2, A2, W2hi + (size_t)l * DD * EM, W2lo + (size_t)l * DD * EM,
          b2 + (size_t)l * DD, Z2f, stats2, NN);
    }
    k_finalize<<<1, 256, 0, stream>>>(stats2, g2 + (size_t)l * DD, be2 + (size_t)l * DD, ss2, DD);
  }
  k_bn_out<DD><<<2048, 256, 0, stream>>>(Z2f, ss2, out, NN * DD / 4);
}

// Round 6
// 1163.928 us; speedup vs baseline: 2.9915x; 1.1395x over previous
//
#include <hip/hip_runtime.h>
#include <stdint.h>

#define NN 50000      // nodes
#define NE 800000     // edges
#define DD 256        // node feature dim
#define EM 512        // MLP hidden dim
#define NL 4          // layers
#define EPS 1e-5f

typedef unsigned short u16;
typedef __attribute__((ext_vector_type(4))) unsigned short u16x4;
typedef __attribute__((ext_vector_type(8))) short s16x8;
typedef __attribute__((ext_vector_type(8))) float f32x8;
typedef __attribute__((ext_vector_type(4))) float f32x4;
typedef __attribute__((ext_vector_type(8))) __bf16 bf16x8;

union Frag { s16x8 s; bf16x8 b; };

__device__ __forceinline__ float bf2f(u16 h) {
  unsigned u = ((unsigned)h) << 16;
  return __builtin_bit_cast(float, u);
}
__device__ __forceinline__ u16 f2bf(float f) {
  unsigned u = __builtin_bit_cast(unsigned, f);
  u = (u + 0x7FFFu + ((u >> 16) & 1u)) >> 16;   // round-nearest-even
  return (u16)u;
}
// split f32 into bf16 hi + bf16 lo with hi+lo ~= f (error ~2^-18 rel)
__device__ __forceinline__ void bfsplit(float f, u16& hi, u16& lo) {
  hi = f2bf(f);
  lo = f2bf(f - bf2f(hi));
}

// async 16B global->LDS (lds base must be wave-uniform; lane i lands at base+16*i)
__device__ __forceinline__ void gload16(const u16* g, u16* l) {
  __builtin_amdgcn_global_load_lds(
      (const __attribute__((address_space(1))) unsigned int*)g,
      (__attribute__((address_space(3))) unsigned int*)l, 16, 0, 0);
}

// ---------------- setup kernels (once per launch) ----------------

__global__ void k_f32_to_bf16(const float* __restrict__ in, u16* __restrict__ out, int n8) {
  int i = blockIdx.x * blockDim.x + threadIdx.x;
  int stride = gridDim.x * blockDim.x;
  for (; i < n8; i += stride) {
    f32x8 v = ((const f32x8*)in)[i];
    s16x8 o;
#pragma unroll
    for (int j = 0; j < 8; j++) o[j] = (short)f2bf(v[j]);
    ((s16x8*)out)[i] = o;
  }
}

// W: (NL, K, Nc) f32 row-major -> WT hi/lo: (NL, Nc, K) bf16 split (N-major)
// coalesced READ (thread i == source index), strided write (stores don't stall)
__global__ void k_prep_w(const float* __restrict__ W, u16* __restrict__ WThi,
                         u16* __restrict__ WTlo, int K, int Nc) {
  int total = NL * K * Nc;
  for (int i = blockIdx.x * blockDim.x + threadIdx.x; i < total; i += gridDim.x * blockDim.x) {
    int l = i / (K * Nc);
    int rem = i - l * (K * Nc);
    int k = rem / Nc;
    int n = rem - k * Nc;
    float v = W[i];
    u16 hi, lo; bfsplit(v, hi, lo);
    size_t o = (size_t)l * Nc * K + (size_t)n * K + k;
    WThi[o] = hi; WTlo[o] = lo;
  }
}

__global__ void k_deg(const int* __restrict__ dst, int* __restrict__ deg) {
  for (int e = blockIdx.x * blockDim.x + threadIdx.x; e < NE; e += gridDim.x * blockDim.x)
    atomicAdd(&deg[dst[e]], 1);
}

__global__ __launch_bounds__(1024) void k_scan(const int* __restrict__ deg, int* __restrict__ rowptr) {
  __shared__ int part[1024];
  int t = threadIdx.x;
  const int CH = (NN + 1023) / 1024;   // 49
  int base = t * CH;
  int s = 0;
  for (int i = 0; i < CH; i++) { int idx = base + i; if (idx < NN) s += deg[idx]; }
  part[t] = s;
  __syncthreads();
  for (int off = 1; off < 1024; off <<= 1) {
    int v = (t >= off) ? part[t - off] : 0;
    __syncthreads();
    part[t] += v;
    __syncthreads();
  }
  int run = part[t] - s;               // exclusive prefix
  for (int i = 0; i < CH; i++) {
    int idx = base + i;
    if (idx < NN) { rowptr[idx] = run; run += deg[idx]; }
  }
  if (t == 1023) rowptr[NN] = part[1023];
}

__global__ void k_fill(const int* __restrict__ src, const int* __restrict__ dst,
                       const int* __restrict__ rowptr, int* __restrict__ cursor,
                       int* __restrict__ cols) {
  for (int e = blockIdx.x * blockDim.x + threadIdx.x; e < NE; e += gridDim.x * blockDim.x) {
    int d = dst[e];
    int pos = atomicAdd(&cursor[d], 1);
    cols[rowptr[d] + pos] = src[e];
  }
}

// ---------------- per-layer kernels ----------------

// GIN aggregation from a bf16 source (512B rows) with optionally fused BN2+ReLU:
//   h_j = FUSED ? relu(src_j*sc+sh) : src_j ;  agg_i = h_i + sum_{j->i} h_j
// one wave per node, bf16 in, split-bf16 out, f32 accumulate.
// Edge loop unrolled x4: 4 independent row gathers in flight per iteration.
template <bool FUSED>
__global__ __launch_bounds__(256) void k_agg(const u16* __restrict__ src,
                                             const float* __restrict__ ss,
                                             const int* __restrict__ rowptr,
                                             const int* __restrict__ cols,
                                             u16* __restrict__ Ahi,
                                             u16* __restrict__ Alo) {
  int wid = threadIdx.x >> 6, lane = threadIdx.x & 63;
  int node = blockIdx.x * 4 + wid;     // NN % 4 == 0
  int c0 = lane << 2;                  // 4 cols per lane covers 256 cols
  f32x4 sc, sh;
  if (FUSED) {
    sc = *(const f32x4*)(ss + c0);
    sh = *(const f32x4*)(ss + DD + c0);
  }
  u16x4 v = *(const u16x4*)(src + (size_t)node * DD + c0);
  f32x4 a;
#pragma unroll
  for (int j = 0; j < 4; j++) {
    float f = bf2f(v[j]);
    a[j] = FUSED ? fmaxf(f * sc[j] + sh[j], 0.f) : f;
  }
  int beg = rowptr[node], end = rowptr[node + 1];
  int e = beg;
  for (; e + 3 < end; e += 4) {
    int s0 = cols[e], s1 = cols[e + 1], s2 = cols[e + 2], s3 = cols[e + 3];
    u16x4 w0 = *(const u16x4*)(src + (size_t)s0 * DD + c0);
    u16x4 w1 = *(const u16x4*)(src + (size_t)s1 * DD + c0);
    u16x4 w2 = *(const u16x4*)(src + (size_t)s2 * DD + c0);
    u16x4 w3 = *(const u16x4*)(src + (size_t)s3 * DD + c0);
#pragma unroll
    for (int j = 0; j < 4; j++) {
      float f0 = bf2f(w0[j]), f1 = bf2f(w1[j]), f2 = bf2f(w2[j]), f3 = bf2f(w3[j]);
      if (FUSED) {
        f0 = fmaxf(f0 * sc[j] + sh[j], 0.f);
        f1 = fmaxf(f1 * sc[j] + sh[j], 0.f);
        f2 = fmaxf(f2 * sc[j] + sh[j], 0.f);
        f3 = fmaxf(f3 * sc[j] + sh[j], 0.f);
      }
      a[j] += f0; a[j] += f1; a[j] += f2; a[j] += f3;
    }
  }
  for (; e < end; ++e) {
    int s = cols[e];
    u16x4 w = *(const u16x4*)(src + (size_t)s * DD + c0);
#pragma unroll
    for (int j = 0; j < 4; j++) {
      float f = bf2f(w[j]);
      a[j] += FUSED ? fmaxf(f * sc[j] + sh[j], 0.f) : f;
    }
  }
  u16x4 oh, ol;
#pragma unroll
  for (int j = 0; j < 4; j++) { u16 hi, lo; bfsplit(a[j], hi, lo); oh[j] = hi; ol[j] = lo; }
  *(u16x4*)(Ahi + (size_t)node * DD + c0) = oh;
  *(u16x4*)(Alo + (size_t)node * DD + c0) = ol;
}

// C(MxNC) = A(MxK) * W(KxNC) + bias via NSEG bf16 MFMA segments:
//   NSEG==3: Ahi*Whi + Alo*Whi + Ahi*Wlo     (A given as split pair)
//   NSEG==2: A*Whi + A*Wlo                   (A plain bf16)
// All operand tiles staged ONCE per K-step (4 or 3 tiles in LDS), all segments
// computed from LDS -> 48 (or 32) MFMA per barrier-pair instead of 16.
// Z output: bf16 (OUT_BF16) or f32. Per-column batch sums/sumsq -> stats[2*NC].
// 128x128 block tile, 4 waves 2x2, K-step 32, linear LDS + global_load_lds.
template <int K, int NC, bool OUT_BF16, int NSEG>
__global__ __launch_bounds__(256) void k_gemm(const u16* __restrict__ Ahi,
                                              const u16* __restrict__ Alo,
                                              const u16* __restrict__ WThi,
                                              const u16* __restrict__ WTlo,
                                              const float* __restrict__ bias,
                                              void* __restrict__ Zout,
                                              float* __restrict__ stats, int M) {
  __shared__ u16 AlHi[128 * 32];
  __shared__ u16 AlLo[NSEG == 3 ? 128 * 32 : 64];
  __shared__ u16 BlHi[128 * 32];
  __shared__ u16 BlLo[128 * 32];
  __shared__ float sblk[256];          // [0..128) col sums, [128..256) col sumsq
  int tid = threadIdx.x;
  sblk[tid] = 0.f;
  int lane = tid & 63, wid = tid >> 6;
  int wm = wid & 1, wn = wid >> 1;
  int brow = blockIdx.x * 128;
  int bcol = blockIdx.y * 128;

  f32x4 zero = {0.f, 0.f, 0.f, 0.f};
  f32x4 acc[4][4];
#pragma unroll
  for (int m = 0; m < 4; m++)
#pragma unroll
    for (int n = 0; n < 4; n++) acc[m][n] = zero;

  // staging: chunk = 16 rows (1KB). wave w stages chunks w and w+4 of each tile.
  int rinc = lane >> 2;                 // row within chunk
  int cq = (lane & 3) * 8;              // 8-ushort (16B) column quarter
  long ra0 = brow + wid * 16 + rinc;  if (ra0 > M - 1) ra0 = M - 1;
  long ra1 = brow + 64 + wid * 16 + rinc; if (ra1 > M - 1) ra1 = M - 1;
  long rb0 = bcol + wid * 16 + rinc;
  long rb1 = bcol + 64 + wid * 16 + rinc;

  const u16* gAh0 = Ahi + ra0 * K + cq;
  const u16* gAh1 = Ahi + ra1 * K + cq;
  const u16* gAl0 = Alo + ra0 * K + cq;
  const u16* gAl1 = Alo + ra1 * K + cq;
  const u16* gBh0 = WThi + rb0 * K + cq;
  const u16* gBh1 = WThi + rb1 * K + cq;
  const u16* gBl0 = WTlo + rb0 * K + cq;
  const u16* gBl1 = WTlo + rb1 * K + cq;
  int lc0 = wid * 512, lc1 = (wid + 4) * 512;   // wave-uniform chunk bases

  int fr = lane & 15;                   // row/col within 16-tile
  int kk = (lane >> 4) * 8;             // k offset
  int fo = (wm * 64 + fr) * 32 + kk;    // A frag offset
  int go = (wn * 64 + fr) * 32 + kk;    // B frag offset

  const int KS = K / 32;
  for (int kt = 0; kt < KS; ++kt) {
    int k0 = kt * 32;
    gload16(gAh0 + k0, &AlHi[lc0]);
    gload16(gAh1 + k0, &AlHi[lc1]);
    if (NSEG == 3) {
      gload16(gAl0 + k0, &AlLo[lc0]);
      gload16(gAl1 + k0, &AlLo[lc1]);
    }
    gload16(gBh0 + k0, &BlHi[lc0]);
    gload16(gBh1 + k0, &BlHi[lc1]);
    gload16(gBl0 + k0, &BlLo[lc0]);
    gload16(gBl1 + k0, &BlLo[lc1]);
    __syncthreads();                    // drains vmcnt (async LDS stores) + barrier

    Frag aH[4], bH[4], bL[4];
#pragma unroll
    for (int m = 0; m < 4; m++) aH[m].s = *(const s16x8*)(&AlHi[fo + m * 512]);
#pragma unroll
    for (int n = 0; n < 4; n++) bH[n].s = *(const s16x8*)(&BlHi[go + n * 512]);
#pragma unroll
    for (int n = 0; n < 4; n++) bL[n].s = *(const s16x8*)(&BlLo[go + n * 512]);
    // seg0: Ahi * Whi
#pragma unroll
    for (int m = 0; m < 4; m++)
#pragma unroll
      for (int n = 0; n < 4; n++)
        acc[m][n] = __builtin_amdgcn_mfma_f32_16x16x32_bf16(aH[m].b, bH[n].b, acc[m][n], 0, 0, 0);
    if (NSEG == 3) {
      Frag aL[4];
#pragma unroll
      for (int m = 0; m < 4; m++) aL[m].s = *(const s16x8*)(&AlLo[fo + m * 512]);
      // seg1: Alo * Whi
#pragma unroll
      for (int m = 0; m < 4; m++)
#pragma unroll
        for (int n = 0; n < 4; n++)
          acc[m][n] = __builtin_amdgcn_mfma_f32_16x16x32_bf16(aL[m].b, bH[n].b, acc[m][n], 0, 0, 0);
    }
    // last seg: Ahi * Wlo
#pragma unroll
    for (int m = 0; m < 4; m++)
#pragma unroll
      for (int n = 0; n < 4; n++)
        acc[m][n] = __builtin_amdgcn_mfma_f32_16x16x32_bf16(aH[m].b, bL[n].b, acc[m][n], 0, 0, 0);
    __syncthreads();                    // all waves done reading before next stage
  }

  // epilogue: D row=(lane>>4)*4+r, col=lane&15 within each 16x16 frag [m89-verified]
  int colb = bcol + wn * 64;
  float bv[4];
#pragma unroll
  for (int n = 0; n < 4; n++) bv[n] = bias[colb + n * 16 + fr];
  int rb = brow + wm * 64 + ((lane >> 4) << 2);
  float sn[4] = {0.f, 0.f, 0.f, 0.f}, qn[4] = {0.f, 0.f, 0.f, 0.f};
#pragma unroll
  for (int m = 0; m < 4; m++) {
#pragma unroll
    for (int r = 0; r < 4; r++) {
      int row = rb + m * 16 + r;
      if (row < M) {
        size_t base = (size_t)row * NC + colb + fr;
#pragma unroll
        for (int n = 0; n < 4; n++) {
          float z = acc[m][n][r] + bv[n];
          if (OUT_BF16) ((u16*)Zout)[base + n * 16] = f2bf(z);
          else          ((float*)Zout)[base + n * 16] = z;
          sn[n] += z; qn[n] += z * z;
        }
      }
    }
  }
  // reduce across the 4 row-groups of the wave (lanes differing in bits 4,5)
#pragma unroll
  for (int n = 0; n < 4; n++) {
    sn[n] += __shfl_xor(sn[n], 16); sn[n] += __shfl_xor(sn[n], 32);
    qn[n] += __shfl_xor(qn[n], 16); qn[n] += __shfl_xor(qn[n], 32);
  }
  if (lane < 16) {
#pragma unroll
    for (int n = 0; n < 4; n++) {
      atomicAdd(&sblk[wn * 64 + n * 16 + lane], sn[n]);
      atomicAdd(&sblk[128 + wn * 64 + n * 16 + lane], qn[n]);
    }
  }
  __syncthreads();
  if (tid < 128) atomicAdd(&stats[bcol + tid], sblk[tid]);
  else           atomicAdd(&stats[NC + bcol + (tid - 128)], sblk[tid]);
}

__global__ void k_finalize(const float* __restrict__ stats, const float* __restrict__ gamma,
                           const float* __restrict__ beta, float* __restrict__ ss, int NC) {
  int c = blockIdx.x * blockDim.x + threadIdx.x;
  if (c < NC) {
    float mean = stats[c] * (1.0f / NN);
    float var = stats[NC + c] * (1.0f / NN) - mean * mean;
    float sc = gamma[c] * rsqrtf(var + EPS);
    ss[c] = sc;
    ss[NC + c] = beta[c] - mean * sc;
  }
}

// BN1 + ReLU on bf16 Z1 -> plain bf16 A2 (GEMM2 input)
template <int NC>
__global__ void k_bn_a2(const u16* __restrict__ Z, const float* __restrict__ ss,
                        u16* __restrict__ A2, int n8) {
  int i = blockIdx.x * blockDim.x + threadIdx.x;
  int stride = gridDim.x * blockDim.x;
  for (; i < n8; i += stride) {
    int c = (i * 8) & (NC - 1);
    s16x8 v = *(const s16x8*)(Z + (size_t)i * 8);
    s16x8 o;
#pragma unroll
    for (int j = 0; j < 8; j++) {
      float f = fmaxf(bf2f((u16)v[j]) * ss[c + j] + ss[NC + c + j], 0.f);
      o[j] = (short)f2bf(f);
    }
    *(s16x8*)(A2 + (size_t)i * 8) = o;
  }
}

// final-layer BN2 (no ReLU) on f32 Z2 -> f32 d_out
template <int NC>
__global__ void k_bn_out(const float* __restrict__ Z, const float* __restrict__ ss,
                         float* __restrict__ out, int n4) {
  int i = blockIdx.x * blockDim.x + threadIdx.x;
  int stride = gridDim.x * blockDim.x;
  for (; i < n4; i += stride) {
    int c = (i * 4) & (NC - 1);
    f32x4 v = *(const f32x4*)(Z + (size_t)i * 4);
    f32x4 o;
#pragma unroll
    for (int j = 0; j < 4; j++) o[j] = v[j] * ss[c + j] + ss[NC + c + j];
    *(f32x4*)(out + (size_t)i * 4) = o;
  }
}

// ---------------- host ----------------

extern "C" void kernel_launch(void* const* d_in, const int* in_sizes, int n_in,
                              void* d_out, int out_size, void* d_ws, size_t ws_size,
                              hipStream_t stream) {
  const float* x  = (const float*)d_in[0];
  const int* ei   = (const int*)d_in[1];
  const int* esrc = ei;
  const int* edst = ei + NE;
  const float* W1 = (const float*)d_in[2];
  const float* b1 = (const float*)d_in[3];
  const float* g1 = (const float*)d_in[4];
  const float* be1= (const float*)d_in[5];
  const float* W2 = (const float*)d_in[6];
  const float* b2 = (const float*)d_in[7];
  const float* g2 = (const float*)d_in[8];
  const float* be2= (const float*)d_in[9];
  float* out = (float*)d_out;

  char* w = (char*)d_ws;
  auto alloc = [&](size_t bytes) {
    char* p = w;
    w += (bytes + 255) & ~(size_t)255;
    return p;
  };
  // Two 51.2MB ping-pong regions (total ws ~110MB; round-5-proven budget):
  //   R0: {xb / Z2bf} (bf16 [NN][256], front) | Z1 (bf16 [NN][512], full) | Z2 f32 (last layer, full)
  //   R1: A1 split pair (bf16 [NN][256] x2) then A2 (bf16 [NN][512])
  char* R0 = alloc((size_t)NN * EM * 2);
  char* R1 = alloc((size_t)NN * EM * 2);
  u16* W1hi = (u16*)alloc((size_t)NL * EM * DD * 2);
  u16* W1lo = (u16*)alloc((size_t)NL * EM * DD * 2);
  u16* W2hi = (u16*)alloc((size_t)NL * DD * EM * 2);
  u16* W2lo = (u16*)alloc((size_t)NL * DD * EM * 2);
  int* deg    = (int*)alloc((size_t)NN * 4);
  int* rowptr = (int*)alloc((size_t)(NN + 1) * 4);
  int* cursor = (int*)alloc((size_t)NN * 4);
  int* cols   = (int*)alloc((size_t)NE * 4);
  float* stats1 = (float*)alloc(2 * EM * 4);
  float* stats2 = (float*)alloc(2 * DD * 4);
  float* ss1    = (float*)alloc(2 * EM * 4);
  float* ss2    = (float*)alloc(2 * DD * 4);

  u16*   Hb   = (u16*)R0;              // bf16 [NN][256]: xb for l=0, Z2bf for l>0
  u16*   Z1   = (u16*)R0;
  float* Z2f  = (float*)R0;            // last layer only
  u16*   A1hi = (u16*)R1;
  u16*   A1lo = (u16*)R1 + (size_t)NN * DD;
  u16*   A2   = (u16*)R1;

  // ---- one-time prep ----
  hipMemsetAsync(deg, 0, (size_t)NN * 4, stream);
  hipMemsetAsync(cursor, 0, (size_t)NN * 4, stream);
  k_deg<<<2048, 256, 0, stream>>>(edst, deg);
  k_scan<<<1, 1024, 0, stream>>>(deg, rowptr);
  k_fill<<<2048, 256, 0, stream>>>(esrc, edst, rowptr, cursor, cols);
  k_prep_w<<<2048, 256, 0, stream>>>(W1, W1hi, W1lo, DD, EM);
  k_prep_w<<<2048, 256, 0, stream>>>(W2, W2hi, W2lo, EM, DD);
  k_f32_to_bf16<<<2048, 256, 0, stream>>>(x, Hb, NN * DD / 8);

  for (int l = 0; l < NL; ++l) {
    // aggregation from bf16 rows (BN2+ReLU of previous layer fused for l>0)
    if (l == 0)
      k_agg<false><<<NN / 4, 256, 0, stream>>>(Hb, nullptr, rowptr, cols, A1hi, A1lo);
    else
      k_agg<true><<<NN / 4, 256, 0, stream>>>(Hb, ss2, rowptr, cols, A1hi, A1lo);

    hipMemsetAsync(stats1, 0, 2 * EM * 4, stream);
    k_gemm<DD, EM, true, 3><<<dim3((NN + 127) / 128, EM / 128), 256, 0, stream>>>(
        A1hi, A1lo, W1hi + (size_t)l * EM * DD, W1lo + (size_t)l * EM * DD,
        b1 + (size_t)l * EM, Z1, stats1, NN);
    k_finalize<<<2, 256, 0, stream>>>(stats1, g1 + (size_t)l * EM, be1 + (size_t)l * EM, ss1, EM);
    k_bn_a2<EM><<<2048, 256, 0, stream>>>(Z1, ss1, A2, NN * EM / 8);

    hipMemsetAsync(stats2, 0, 2 * DD * 4, stream);
    if (l < NL - 1) {
      // Z2 stored as plain bf16 (pre-BN) -> next layer's gather source
      k_gemm<EM, DD, true, 2><<<dim3((NN + 127) / 128, DD / 128), 256, 0, stream>>>(
          A2, A2, W2hi + (size_t)l * DD * EM, W2lo + (size_t)l * DD * EM,
          b2 + (size_t)l * DD, Hb, stats2, NN);
    } else {
      k_gemm<EM, DD, false, 2><<<dim3((NN + 127) / 128, DD / 128), 256, 0, stream>>>(
          A2, A2, W2hi + (size_t)l * DD * EM, W2lo + (size_t)l * DD * EM,
          b2 + (size_t)l * DD, Z2f, stats2, NN);
    }
    k_finalize<<<1, 256, 0, stream>>>(stats2, g2 + (size_t)l * DD, be2 + (size_t)l * DD, ss2, DD);
  }
  k_bn_out<DD><<<2048, 256, 0, stream>>>(Z2f, ss2, out, NN * DD / 4);
}

// Round 7
// 980.319 us; speedup vs baseline: 3.5518x; 1.1873x over previous
//
#include <hip/hip_runtime.h>
#include <stdint.h>

#define NN 50000      // nodes
#define NE 800000     // edges
#define DD 256        // node feature dim
#define EM 512        // MLP hidden dim
#define NL 4          // layers
#define EPS 1e-5f

typedef unsigned short u16;
typedef __attribute__((ext_vector_type(4))) unsigned short u16x4;
typedef __attribute__((ext_vector_type(8))) short s16x8;
typedef __attribute__((ext_vector_type(8))) float f32x8;
typedef __attribute__((ext_vector_type(4))) float f32x4;
typedef __attribute__((ext_vector_type(8))) __bf16 bf16x8;

union Frag { s16x8 s; bf16x8 b; };

__device__ __forceinline__ float bf2f(u16 h) {
  unsigned u = ((unsigned)h) << 16;
  return __builtin_bit_cast(float, u);
}
__device__ __forceinline__ u16 f2bf(float f) {
  unsigned u = __builtin_bit_cast(unsigned, f);
  u = (u + 0x7FFFu + ((u >> 16) & 1u)) >> 16;   // round-nearest-even
  return (u16)u;
}
// split f32 into bf16 hi + bf16 lo with hi+lo ~= f (error ~2^-18 rel)
__device__ __forceinline__ void bfsplit(float f, u16& hi, u16& lo) {
  hi = f2bf(f);
  lo = f2bf(f - bf2f(hi));
}

// async 16B global->LDS (lds base must be wave-uniform; lane i lands at base+16*i)
__device__ __forceinline__ void gload16(const u16* g, u16* l) {
  __builtin_amdgcn_global_load_lds(
      (const __attribute__((address_space(1))) unsigned int*)g,
      (__attribute__((address_space(3))) unsigned int*)l, 16, 0, 0);
}

// ---------------- setup kernels (once per launch) ----------------

__global__ void k_f32_to_bf16(const float* __restrict__ in, u16* __restrict__ out, int n8) {
  int i = blockIdx.x * blockDim.x + threadIdx.x;
  int stride = gridDim.x * blockDim.x;
  for (; i < n8; i += stride) {
    f32x8 v = ((const f32x8*)in)[i];
    s16x8 o;
#pragma unroll
    for (int j = 0; j < 8; j++) o[j] = (short)f2bf(v[j]);
    ((s16x8*)out)[i] = o;
  }
}

// W: (NL, K, Nc) f32 row-major -> WT hi/lo: (NL, Nc, K) bf16 split (N-major)
// coalesced READ (thread i == source index), strided write (stores don't stall)
__global__ void k_prep_w(const float* __restrict__ W, u16* __restrict__ WThi,
                         u16* __restrict__ WTlo, int K, int Nc) {
  int total = NL * K * Nc;
  for (int i = blockIdx.x * blockDim.x + threadIdx.x; i < total; i += gridDim.x * blockDim.x) {
    int l = i / (K * Nc);
    int rem = i - l * (K * Nc);
    int k = rem / Nc;
    int n = rem - k * Nc;
    float v = W[i];
    u16 hi, lo; bfsplit(v, hi, lo);
    size_t o = (size_t)l * Nc * K + (size_t)n * K + k;
    WThi[o] = hi; WTlo[o] = lo;
  }
}

__global__ void k_deg(const int* __restrict__ dst, int* __restrict__ deg) {
  for (int e = blockIdx.x * blockDim.x + threadIdx.x; e < NE; e += gridDim.x * blockDim.x)
    atomicAdd(&deg[dst[e]], 1);
}

// ---- parallel exclusive scan of deg[NN] -> rowptr (3 phases) ----
#define SCB 49   // ceil(NN/1024)

__global__ __launch_bounds__(1024) void k_scan1(const int* __restrict__ deg,
                                                int* __restrict__ rowptr,
                                                int* __restrict__ part) {
  __shared__ int sm[1024];
  int t = threadIdx.x, b = blockIdx.x;
  int idx = b * 1024 + t;
  int v = (idx < NN) ? deg[idx] : 0;
  sm[t] = v;
  __syncthreads();
  for (int off = 1; off < 1024; off <<= 1) {
    int u = (t >= off) ? sm[t - off] : 0;
    __syncthreads();
    sm[t] += u;
    __syncthreads();
  }
  int incl = sm[t];
  if (idx < NN) rowptr[idx] = incl - v;      // local exclusive prefix
  if (t == 1023) part[b] = incl;             // block total
}

__global__ void k_scan2(int* __restrict__ part, int* __restrict__ rowptr) {
  int t = threadIdx.x;                       // 64 threads = 1 wave
  int v = (t < SCB) ? part[t] : 0;
  int orig = v;
  for (int off = 1; off < 64; off <<= 1) {
    int u = __shfl_up(v, off);
    if (t >= off) v += u;
  }
  if (t < SCB) part[t] = v - orig;           // exclusive block offset
  if (t == SCB - 1) rowptr[NN] = v;          // grand total == NE
}

__global__ __launch_bounds__(1024) void k_scan3(int* __restrict__ rowptr,
                                                const int* __restrict__ part) {
  int idx = blockIdx.x * 1024 + threadIdx.x;
  if (idx < NN) rowptr[idx] += part[blockIdx.x];
}

__global__ void k_fill(const int* __restrict__ src, const int* __restrict__ dst,
                       const int* __restrict__ rowptr, int* __restrict__ cursor,
                       int* __restrict__ cols) {
  for (int e = blockIdx.x * blockDim.x + threadIdx.x; e < NE; e += gridDim.x * blockDim.x) {
    int d = dst[e];
    int pos = atomicAdd(&cursor[d], 1);
    cols[rowptr[d] + pos] = src[e];
  }
}

// ---------------- per-layer kernels ----------------

// GIN aggregation from a bf16 source (512B rows) with optionally fused BN2+ReLU:
//   h_j = FUSED ? relu(src_j*sc+sh) : src_j ;  agg_i = h_i + sum_{j->i} h_j
// one wave per node, bf16 in, split-bf16 out, f32 accumulate.
// Edge loop unrolled x4: 4 independent row gathers in flight per iteration.
template <bool FUSED>
__global__ __launch_bounds__(256) void k_agg(const u16* __restrict__ src,
                                             const float* __restrict__ ss,
                                             const int* __restrict__ rowptr,
                                             const int* __restrict__ cols,
                                             u16* __restrict__ Ahi,
                                             u16* __restrict__ Alo) {
  int wid = threadIdx.x >> 6, lane = threadIdx.x & 63;
  int node = blockIdx.x * 4 + wid;     // NN % 4 == 0
  int c0 = lane << 2;                  // 4 cols per lane covers 256 cols
  f32x4 sc, sh;
  if (FUSED) {
    sc = *(const f32x4*)(ss + c0);
    sh = *(const f32x4*)(ss + DD + c0);
  }
  u16x4 v = *(const u16x4*)(src + (size_t)node * DD + c0);
  f32x4 a;
#pragma unroll
  for (int j = 0; j < 4; j++) {
    float f = bf2f(v[j]);
    a[j] = FUSED ? fmaxf(f * sc[j] + sh[j], 0.f) : f;
  }
  int beg = rowptr[node], end = rowptr[node + 1];
  int e = beg;
  for (; e + 3 < end; e += 4) {
    int s0 = cols[e], s1 = cols[e + 1], s2 = cols[e + 2], s3 = cols[e + 3];
    u16x4 w0 = *(const u16x4*)(src + (size_t)s0 * DD + c0);
    u16x4 w1 = *(const u16x4*)(src + (size_t)s1 * DD + c0);
    u16x4 w2 = *(const u16x4*)(src + (size_t)s2 * DD + c0);
    u16x4 w3 = *(const u16x4*)(src + (size_t)s3 * DD + c0);
#pragma unroll
    for (int j = 0; j < 4; j++) {
      float f0 = bf2f(w0[j]), f1 = bf2f(w1[j]), f2 = bf2f(w2[j]), f3 = bf2f(w3[j]);
      if (FUSED) {
        f0 = fmaxf(f0 * sc[j] + sh[j], 0.f);
        f1 = fmaxf(f1 * sc[j] + sh[j], 0.f);
        f2 = fmaxf(f2 * sc[j] + sh[j], 0.f);
        f3 = fmaxf(f3 * sc[j] + sh[j], 0.f);
      }
      a[j] += f0; a[j] += f1; a[j] += f2; a[j] += f3;
    }
  }
  for (; e < end; ++e) {
    int s = cols[e];
    u16x4 w = *(const u16x4*)(src + (size_t)s * DD + c0);
#pragma unroll
    for (int j = 0; j < 4; j++) {
      float f = bf2f(w[j]);
      a[j] += FUSED ? fmaxf(f * sc[j] + sh[j], 0.f) : f;
    }
  }
  u16x4 oh, ol;
#pragma unroll
  for (int j = 0; j < 4; j++) { u16 hi, lo; bfsplit(a[j], hi, lo); oh[j] = hi; ol[j] = lo; }
  *(u16x4*)(Ahi + (size_t)node * DD + c0) = oh;
  *(u16x4*)(Alo + (size_t)node * DD + c0) = ol;
}

// C(MxNC) = A(MxK) * W(KxNC) + bias via NSEG bf16 MFMA segments (see r6).
// 1D grid with XCD-aware mapping: the NC/128 col-blocks of one row-panel get
// linear ids differing by 8 -> same XCD (round-robin) -> A-panel shared in L2.
template <int K, int NC, bool OUT_BF16, int NSEG>
__global__ __launch_bounds__(256) void k_gemm(const u16* __restrict__ Ahi,
                                              const u16* __restrict__ Alo,
                                              const u16* __restrict__ WThi,
                                              const u16* __restrict__ WTlo,
                                              const float* __restrict__ bias,
                                              void* __restrict__ Zout,
                                              float* __restrict__ stats, int M) {
  constexpr int NCB = NC / 128;        // 4 or 2 (power of 2)
  int nxb = (M + 127) >> 7;
  int bid = blockIdx.x;
  int slot = bid & 7;
  int ycb  = (bid >> 3) & (NCB - 1);
  int grp  = bid / (8 * NCB);
  int xb   = grp * 8 + slot;
  if (xb >= nxb) return;
  int brow = xb * 128;
  int bcol = ycb * 128;

  __shared__ u16 AlHi[128 * 32];
  __shared__ u16 AlLo[NSEG == 3 ? 128 * 32 : 64];
  __shared__ u16 BlHi[128 * 32];
  __shared__ u16 BlLo[128 * 32];
  __shared__ float sblk[256];          // [0..128) col sums, [128..256) col sumsq
  int tid = threadIdx.x;
  sblk[tid] = 0.f;
  int lane = tid & 63, wid = tid >> 6;
  int wm = wid & 1, wn = wid >> 1;

  f32x4 zero = {0.f, 0.f, 0.f, 0.f};
  f32x4 acc[4][4];
#pragma unroll
  for (int m = 0; m < 4; m++)
#pragma unroll
    for (int n = 0; n < 4; n++) acc[m][n] = zero;

  // staging: chunk = 16 rows (1KB). wave w stages chunks w and w+4 of each tile.
  int rinc = lane >> 2;                 // row within chunk
  int cq = (lane & 3) * 8;              // 8-ushort (16B) column quarter
  long ra0 = brow + wid * 16 + rinc;  if (ra0 > M - 1) ra0 = M - 1;
  long ra1 = brow + 64 + wid * 16 + rinc; if (ra1 > M - 1) ra1 = M - 1;
  long rb0 = bcol + wid * 16 + rinc;
  long rb1 = bcol + 64 + wid * 16 + rinc;

  const u16* gAh0 = Ahi + ra0 * K + cq;
  const u16* gAh1 = Ahi + ra1 * K + cq;
  const u16* gAl0 = Alo + ra0 * K + cq;
  const u16* gAl1 = Alo + ra1 * K + cq;
  const u16* gBh0 = WThi + rb0 * K + cq;
  const u16* gBh1 = WThi + rb1 * K + cq;
  const u16* gBl0 = WTlo + rb0 * K + cq;
  const u16* gBl1 = WTlo + rb1 * K + cq;
  int lc0 = wid * 512, lc1 = (wid + 4) * 512;   // wave-uniform chunk bases

  int fr = lane & 15;                   // row/col within 16-tile
  int kk = (lane >> 4) * 8;             // k offset
  int fo = (wm * 64 + fr) * 32 + kk;    // A frag offset
  int go = (wn * 64 + fr) * 32 + kk;    // B frag offset

  const int KS = K / 32;
  for (int kt = 0; kt < KS; ++kt) {
    int k0 = kt * 32;
    gload16(gAh0 + k0, &AlHi[lc0]);
    gload16(gAh1 + k0, &AlHi[lc1]);
    if (NSEG == 3) {
      gload16(gAl0 + k0, &AlLo[lc0]);
      gload16(gAl1 + k0, &AlLo[lc1]);
    }
    gload16(gBh0 + k0, &BlHi[lc0]);
    gload16(gBh1 + k0, &BlHi[lc1]);
    gload16(gBl0 + k0, &BlLo[lc0]);
    gload16(gBl1 + k0, &BlLo[lc1]);
    __syncthreads();                    // drains vmcnt (async LDS stores) + barrier

    Frag aH[4], bH[4], bL[4];
#pragma unroll
    for (int m = 0; m < 4; m++) aH[m].s = *(const s16x8*)(&AlHi[fo + m * 512]);
#pragma unroll
    for (int n = 0; n < 4; n++) bH[n].s = *(const s16x8*)(&BlHi[go + n * 512]);
#pragma unroll
    for (int n = 0; n < 4; n++) bL[n].s = *(const s16x8*)(&BlLo[go + n * 512]);
    // seg0: Ahi * Whi
#pragma unroll
    for (int m = 0; m < 4; m++)
#pragma unroll
      for (int n = 0; n < 4; n++)
        acc[m][n] = __builtin_amdgcn_mfma_f32_16x16x32_bf16(aH[m].b, bH[n].b, acc[m][n], 0, 0, 0);
    if (NSEG == 3) {
      Frag aL[4];
#pragma unroll
      for (int m = 0; m < 4; m++) aL[m].s = *(const s16x8*)(&AlLo[fo + m * 512]);
      // seg1: Alo * Whi
#pragma unroll
      for (int m = 0; m < 4; m++)
#pragma unroll
        for (int n = 0; n < 4; n++)
          acc[m][n] = __builtin_amdgcn_mfma_f32_16x16x32_bf16(aL[m].b, bH[n].b, acc[m][n], 0, 0, 0);
    }
    // last seg: Ahi * Wlo
#pragma unroll
    for (int m = 0; m < 4; m++)
#pragma unroll
      for (int n = 0; n < 4; n++)
        acc[m][n] = __builtin_amdgcn_mfma_f32_16x16x32_bf16(aH[m].b, bL[n].b, acc[m][n], 0, 0, 0);
    __syncthreads();                    // all waves done reading before next stage
  }

  // epilogue: D row=(lane>>4)*4+r, col=lane&15 within each 16x16 frag [m89-verified]
  int colb = bcol + wn * 64;
  float bv[4];
#pragma unroll
  for (int n = 0; n < 4; n++) bv[n] = bias[colb + n * 16 + fr];
  int rb = brow + wm * 64 + ((lane >> 4) << 2);
  float sn[4] = {0.f, 0.f, 0.f, 0.f}, qn[4] = {0.f, 0.f, 0.f, 0.f};
#pragma unroll
  for (int m = 0; m < 4; m++) {
#pragma unroll
    for (int r = 0; r < 4; r++) {
      int row = rb + m * 16 + r;
      if (row < M) {
        size_t base = (size_t)row * NC + colb + fr;
#pragma unroll
        for (int n = 0; n < 4; n++) {
          float z = acc[m][n][r] + bv[n];
          if (OUT_BF16) ((u16*)Zout)[base + n * 16] = f2bf(z);
          else          ((float*)Zout)[base + n * 16] = z;
          sn[n] += z; qn[n] += z * z;
        }
      }
    }
  }
  // reduce across the 4 row-groups of the wave (lanes differing in bits 4,5)
#pragma unroll
  for (int n = 0; n < 4; n++) {
    sn[n] += __shfl_xor(sn[n], 16); sn[n] += __shfl_xor(sn[n], 32);
    qn[n] += __shfl_xor(qn[n], 16); qn[n] += __shfl_xor(qn[n], 32);
  }
  if (lane < 16) {
#pragma unroll
    for (int n = 0; n < 4; n++) {
      atomicAdd(&sblk[wn * 64 + n * 16 + lane], sn[n]);
      atomicAdd(&sblk[128 + wn * 64 + n * 16 + lane], qn[n]);
    }
  }
  __syncthreads();
  if (tid < 128) atomicAdd(&stats[bcol + tid], sblk[tid]);
  else           atomicAdd(&stats[NC + bcol + (tid - 128)], sblk[tid]);
}

__global__ void k_finalize(const float* __restrict__ stats, const float* __restrict__ gamma,
                           const float* __restrict__ beta, float* __restrict__ ss, int NC) {
  int c = blockIdx.x * blockDim.x + threadIdx.x;
  if (c < NC) {
    float mean = stats[c] * (1.0f / NN);
    float var = stats[NC + c] * (1.0f / NN) - mean * mean;
    float sc = gamma[c] * rsqrtf(var + EPS);
    ss[c] = sc;
    ss[NC + c] = beta[c] - mean * sc;
  }
}

// BN1 + ReLU on bf16 Z1 -> plain bf16 A2 (GEMM2 input)
template <int NC>
__global__ void k_bn_a2(const u16* __restrict__ Z, const float* __restrict__ ss,
                        u16* __restrict__ A2, int n8) {
  int i = blockIdx.x * blockDim.x + threadIdx.x;
  int stride = gridDim.x * blockDim.x;
  for (; i < n8; i += stride) {
    int c = (i * 8) & (NC - 1);
    s16x8 v = *(const s16x8*)(Z + (size_t)i * 8);
    s16x8 o;
#pragma unroll
    for (int j = 0; j < 8; j++) {
      float f = fmaxf(bf2f((u16)v[j]) * ss[c + j] + ss[NC + c + j], 0.f);
      o[j] = (short)f2bf(f);
    }
    *(s16x8*)(A2 + (size_t)i * 8) = o;
  }
}

// final-layer BN2 (no ReLU) on f32 Z2 -> f32 d_out
template <int NC>
__global__ void k_bn_out(const float* __restrict__ Z, const float* __restrict__ ss,
                         float* __restrict__ out, int n4) {
  int i = blockIdx.x * blockDim.x + threadIdx.x;
  int stride = gridDim.x * blockDim.x;
  for (; i < n4; i += stride) {
    int c = (i * 4) & (NC - 1);
    f32x4 v = *(const f32x4*)(Z + (size_t)i * 4);
    f32x4 o;
#pragma unroll
    for (int j = 0; j < 4; j++) o[j] = v[j] * ss[c + j] + ss[NC + c + j];
    *(f32x4*)(out + (size_t)i * 4) = o;
  }
}

// ---------------- host ----------------

extern "C" void kernel_launch(void* const* d_in, const int* in_sizes, int n_in,
                              void* d_out, int out_size, void* d_ws, size_t ws_size,
                              hipStream_t stream) {
  const float* x  = (const float*)d_in[0];
  const int* ei   = (const int*)d_in[1];
  const int* esrc = ei;
  const int* edst = ei + NE;
  const float* W1 = (const float*)d_in[2];
  const float* b1 = (const float*)d_in[3];
  const float* g1 = (const float*)d_in[4];
  const float* be1= (const float*)d_in[5];
  const float* W2 = (const float*)d_in[6];
  const float* b2 = (const float*)d_in[7];
  const float* g2 = (const float*)d_in[8];
  const float* be2= (const float*)d_in[9];
  float* out = (float*)d_out;

  char* w = (char*)d_ws;
  auto alloc = [&](size_t bytes) {
    char* p = w;
    w += (bytes + 255) & ~(size_t)255;
    return p;
  };
  // Two 51.2MB ping-pong regions (proven ws budget ~110MB):
  //   R0: {xb / Z2bf} (bf16 [NN][256], front) | Z1 (bf16 [NN][512], full) | Z2 f32 (last layer, full)
  //   R1: A1 split pair (bf16 [NN][256] x2) then A2 (bf16 [NN][512])
  char* R0 = alloc((size_t)NN * EM * 2);
  char* R1 = alloc((size_t)NN * EM * 2);
  u16* W1hi = (u16*)alloc((size_t)NL * EM * DD * 2);
  u16* W1lo = (u16*)alloc((size_t)NL * EM * DD * 2);
  u16* W2hi = (u16*)alloc((size_t)NL * DD * EM * 2);
  u16* W2lo = (u16*)alloc((size_t)NL * DD * EM * 2);
  // ---- contiguous zero-region: deg | cursor | stats1[NL] | stats2[NL] ----
  char* zbase = (char*)alloc((size_t)NN * 4);             // deg
  int* deg    = (int*)zbase;
  int* cursor = (int*)alloc((size_t)NN * 4);
  float* stats1 = (float*)alloc((size_t)NL * 2 * EM * 4);
  float* stats2 = (float*)alloc((size_t)NL * 2 * DD * 4);
  size_t zspan = (char*)w - zbase;
  // ---- rest ----
  int* rowptr = (int*)alloc((size_t)(NN + 1) * 4);
  int* part   = (int*)alloc(64 * 4);
  int* cols   = (int*)alloc((size_t)NE * 4);
  float* ss1  = (float*)alloc(2 * EM * 4);
  float* ss2  = (float*)alloc(2 * DD * 4);

  u16*   Hb   = (u16*)R0;              // bf16 [NN][256]: xb for l=0, Z2bf for l>0
  u16*   Z1   = (u16*)R0;
  float* Z2f  = (float*)R0;            // last layer only
  u16*   A1hi = (u16*)R1;
  u16*   A1lo = (u16*)R1 + (size_t)NN * DD;
  u16*   A2   = (u16*)R1;

  // ---- one-time prep ----
  hipMemsetAsync(zbase, 0, zspan, stream);                // deg+cursor+all stats
  k_deg<<<2048, 256, 0, stream>>>(edst, deg);
  k_scan1<<<SCB, 1024, 0, stream>>>(deg, rowptr, part);
  k_scan2<<<1, 64, 0, stream>>>(part, rowptr);
  k_scan3<<<SCB, 1024, 0, stream>>>(rowptr, part);
  k_fill<<<2048, 256, 0, stream>>>(esrc, edst, rowptr, cursor, cols);
  k_prep_w<<<2048, 256, 0, stream>>>(W1, W1hi, W1lo, DD, EM);
  k_prep_w<<<2048, 256, 0, stream>>>(W2, W2hi, W2lo, EM, DD);
  k_f32_to_bf16<<<2048, 256, 0, stream>>>(x, Hb, NN * DD / 8);

  const int NXB = (NN + 127) / 128;                       // 391
  const int G1GRID = ((NXB + 7) / 8) * 8 * (EM / 128);    // 49*32 = 1568
  const int G2GRID = ((NXB + 7) / 8) * 8 * (DD / 128);    // 49*16 = 784

  for (int l = 0; l < NL; ++l) {
    float* st1 = stats1 + (size_t)l * 2 * EM;
    float* st2 = stats2 + (size_t)l * 2 * DD;
    // aggregation from bf16 rows (BN2+ReLU of previous layer fused for l>0)
    if (l == 0)
      k_agg<false><<<NN / 4, 256, 0, stream>>>(Hb, nullptr, rowptr, cols, A1hi, A1lo);
    else
      k_agg<true><<<NN / 4, 256, 0, stream>>>(Hb, ss2, rowptr, cols, A1hi, A1lo);

    k_gemm<DD, EM, true, 3><<<G1GRID, 256, 0, stream>>>(
        A1hi, A1lo, W1hi + (size_t)l * EM * DD, W1lo + (size_t)l * EM * DD,
        b1 + (size_t)l * EM, Z1, st1, NN);
    k_finalize<<<2, 256, 0, stream>>>(st1, g1 + (size_t)l * EM, be1 + (size_t)l * EM, ss1, EM);
    k_bn_a2<EM><<<2048, 256, 0, stream>>>(Z1, ss1, A2, NN * EM / 8);

    if (l < NL - 1) {
      // Z2 stored as plain bf16 (pre-BN) -> next layer's gather source
      k_gemm<EM, DD, true, 2><<<G2GRID, 256, 0, stream>>>(
          A2, A2, W2hi + (size_t)l * DD * EM, W2lo + (size_t)l * DD * EM,
          b2 + (size_t)l * DD, Hb, st2, NN);
    } else {
      k_gemm<EM, DD, false, 2><<<G2GRID, 256, 0, stream>>>(
          A2, A2, W2hi + (size_t)l * DD * EM, W2lo + (size_t)l * DD * EM,
          b2 + (size_t)l * DD, Z2f, st2, NN);
    }
    k_finalize<<<1, 256, 0, stream>>>(st2, g2 + (size_t)l * DD, be2 + (size_t)l * DD, ss2, DD);
  }
  k_bn_out<DD><<<2048, 256, 0, stream>>>(Z2f, ss2, out, NN * DD / 4);
}

// Round 8
// 950.749 us; speedup vs baseline: 3.6623x; 1.0311x over previous
//
#include <hip/hip_runtime.h>
#include <stdint.h>

#define NN 50000      // nodes
#define NE 800000     // edges
#define DD 256        // node feature dim
#define EM 512        // MLP hidden dim
#define NL 4          // layers
#define EPS 1e-5f
#define RN (1.0f / NN)

typedef unsigned short u16;
typedef __attribute__((ext_vector_type(4))) unsigned short u16x4;
typedef __attribute__((ext_vector_type(8))) short s16x8;
typedef __attribute__((ext_vector_type(8))) float f32x8;
typedef __attribute__((ext_vector_type(4))) float f32x4;
typedef __attribute__((ext_vector_type(8))) __bf16 bf16x8;

union Frag { s16x8 s; bf16x8 b; };

__device__ __forceinline__ float bf2f(u16 h) {
  unsigned u = ((unsigned)h) << 16;
  return __builtin_bit_cast(float, u);
}
__device__ __forceinline__ u16 f2bf(float f) {
  unsigned u = __builtin_bit_cast(unsigned, f);
  u = (u + 0x7FFFu + ((u >> 16) & 1u)) >> 16;   // round-nearest-even
  return (u16)u;
}
// split f32 into bf16 hi + bf16 lo with hi+lo ~= f (error ~2^-18 rel)
__device__ __forceinline__ void bfsplit(float f, u16& hi, u16& lo) {
  hi = f2bf(f);
  lo = f2bf(f - bf2f(hi));
}

// async 16B global->LDS (lds base must be wave-uniform; lane i lands at base+16*i)
__device__ __forceinline__ void gload16(const u16* g, u16* l) {
  __builtin_amdgcn_global_load_lds(
      (const __attribute__((address_space(1))) unsigned int*)g,
      (__attribute__((address_space(3))) unsigned int*)l, 16, 0, 0);
}

// ---------------- setup kernels (once per launch) ----------------

__global__ void k_f32_to_bf16(const float* __restrict__ in, u16* __restrict__ out, int n8) {
  int i = blockIdx.x * blockDim.x + threadIdx.x;
  int stride = gridDim.x * blockDim.x;
  for (; i < n8; i += stride) {
    f32x8 v = ((const f32x8*)in)[i];
    s16x8 o;
#pragma unroll
    for (int j = 0; j < 8; j++) o[j] = (short)f2bf(v[j]);
    ((s16x8*)out)[i] = o;
  }
}

// W: (NL, K, Nc) f32 row-major -> WT hi/lo: (NL, Nc, K) bf16 split (N-major)
__global__ void k_prep_w(const float* __restrict__ W, u16* __restrict__ WThi,
                         u16* __restrict__ WTlo, int K, int Nc) {
  int total = NL * K * Nc;
  for (int i = blockIdx.x * blockDim.x + threadIdx.x; i < total; i += gridDim.x * blockDim.x) {
    int l = i / (K * Nc);
    int rem = i - l * (K * Nc);
    int k = rem / Nc;
    int n = rem - k * Nc;
    float v = W[i];
    u16 hi, lo; bfsplit(v, hi, lo);
    size_t o = (size_t)l * Nc * K + (size_t)n * K + k;
    WThi[o] = hi; WTlo[o] = lo;
  }
}

__global__ void k_deg(const int* __restrict__ dst, int* __restrict__ deg) {
  for (int e = blockIdx.x * blockDim.x + threadIdx.x; e < NE; e += gridDim.x * blockDim.x)
    atomicAdd(&deg[dst[e]], 1);
}

// ---- parallel exclusive scan of deg[NN] -> rowptr (3 phases) ----
#define SCB 49   // ceil(NN/1024)

__global__ __launch_bounds__(1024) void k_scan1(const int* __restrict__ deg,
                                                int* __restrict__ rowptr,
                                                int* __restrict__ part) {
  __shared__ int sm[1024];
  int t = threadIdx.x, b = blockIdx.x;
  int idx = b * 1024 + t;
  int v = (idx < NN) ? deg[idx] : 0;
  sm[t] = v;
  __syncthreads();
  for (int off = 1; off < 1024; off <<= 1) {
    int u = (t >= off) ? sm[t - off] : 0;
    __syncthreads();
    sm[t] += u;
    __syncthreads();
  }
  int incl = sm[t];
  if (idx < NN) rowptr[idx] = incl - v;      // local exclusive prefix
  if (t == 1023) part[b] = incl;             // block total
}

__global__ void k_scan2(int* __restrict__ part, int* __restrict__ rowptr) {
  int t = threadIdx.x;                       // 64 threads = 1 wave
  int v = (t < SCB) ? part[t] : 0;
  int orig = v;
  for (int off = 1; off < 64; off <<= 1) {
    int u = __shfl_up(v, off);
    if (t >= off) v += u;
  }
  if (t < SCB) part[t] = v - orig;           // exclusive block offset
  if (t == SCB - 1) rowptr[NN] = v;          // grand total == NE
}

__global__ __launch_bounds__(1024) void k_scan3(int* __restrict__ rowptr,
                                                const int* __restrict__ part) {
  int idx = blockIdx.x * 1024 + threadIdx.x;
  if (idx < NN) rowptr[idx] += part[blockIdx.x];
}

__global__ void k_fill(const int* __restrict__ src, const int* __restrict__ dst,
                       const int* __restrict__ rowptr, int* __restrict__ cursor,
                       int* __restrict__ cols) {
  for (int e = blockIdx.x * blockDim.x + threadIdx.x; e < NE; e += gridDim.x * blockDim.x) {
    int d = dst[e];
    int pos = atomicAdd(&cursor[d], 1);
    cols[rowptr[d] + pos] = src[e];
  }
}

// ---------------- per-layer kernels ----------------

// GIN aggregation from bf16 H2 (512B rows); FUSED: apply prev layer's BN2+ReLU
// (sc/sh computed inline from stats — bitwise same as the old finalize path).
// one wave per node, edge loop unrolled x4, f32 accumulate, split-bf16 out.
template <bool FUSED>
__global__ __launch_bounds__(256) void k_agg(const u16* __restrict__ src,
                                             const float* __restrict__ st,
                                             const float* __restrict__ ga,
                                             const float* __restrict__ be,
                                             const int* __restrict__ rowptr,
                                             const int* __restrict__ cols,
                                             u16* __restrict__ Ahi,
                                             u16* __restrict__ Alo) {
  int wid = threadIdx.x >> 6, lane = threadIdx.x & 63;
  int node = blockIdx.x * 4 + wid;     // NN % 4 == 0
  int c0 = lane << 2;                  // 4 cols per lane covers 256 cols
  f32x4 sc, sh;
  if (FUSED) {
    f32x4 m = *(const f32x4*)(st + c0);
    f32x4 q = *(const f32x4*)(st + DD + c0);
    f32x4 g = *(const f32x4*)(ga + c0);
    f32x4 b = *(const f32x4*)(be + c0);
#pragma unroll
    for (int j = 0; j < 4; j++) {
      float mean = m[j] * RN;
      float var = q[j] * RN - mean * mean;
      sc[j] = g[j] * rsqrtf(var + EPS);
      sh[j] = b[j] - mean * sc[j];
    }
  }
  u16x4 v = *(const u16x4*)(src + (size_t)node * DD + c0);
  f32x4 a;
#pragma unroll
  for (int j = 0; j < 4; j++) {
    float f = bf2f(v[j]);
    a[j] = FUSED ? fmaxf(f * sc[j] + sh[j], 0.f) : f;
  }
  int beg = rowptr[node], end = rowptr[node + 1];
  int e = beg;
  for (; e + 3 < end; e += 4) {
    int s0 = cols[e], s1 = cols[e + 1], s2 = cols[e + 2], s3 = cols[e + 3];
    u16x4 w0 = *(const u16x4*)(src + (size_t)s0 * DD + c0);
    u16x4 w1 = *(const u16x4*)(src + (size_t)s1 * DD + c0);
    u16x4 w2 = *(const u16x4*)(src + (size_t)s2 * DD + c0);
    u16x4 w3 = *(const u16x4*)(src + (size_t)s3 * DD + c0);
#pragma unroll
    for (int j = 0; j < 4; j++) {
      float f0 = bf2f(w0[j]), f1 = bf2f(w1[j]), f2 = bf2f(w2[j]), f3 = bf2f(w3[j]);
      if (FUSED) {
        f0 = fmaxf(f0 * sc[j] + sh[j], 0.f);
        f1 = fmaxf(f1 * sc[j] + sh[j], 0.f);
        f2 = fmaxf(f2 * sc[j] + sh[j], 0.f);
        f3 = fmaxf(f3 * sc[j] + sh[j], 0.f);
      }
      a[j] += f0; a[j] += f1; a[j] += f2; a[j] += f3;
    }
  }
  for (; e < end; ++e) {
    int s = cols[e];
    u16x4 w = *(const u16x4*)(src + (size_t)s * DD + c0);
#pragma unroll
    for (int j = 0; j < 4; j++) {
      float f = bf2f(w[j]);
      a[j] += FUSED ? fmaxf(f * sc[j] + sh[j], 0.f) : f;
    }
  }
  u16x4 oh, ol;
#pragma unroll
  for (int j = 0; j < 4; j++) { u16 hi, lo; bfsplit(a[j], hi, lo); oh[j] = hi; ol[j] = lo; }
  *(u16x4*)(Ahi + (size_t)node * DD + c0) = oh;
  *(u16x4*)(Alo + (size_t)node * DD + c0) = ol;
}

// GEMM1: Z1(Mx512) = A1(Mx256)*W1 + b1 via 3 bf16 segments (Ahi*Whi+Alo*Whi+Ahi*Wlo),
// all tiles staged once per K-step. bf16 out + column stats. 1D XCD-aware grid.
template <int K, int NC>
__global__ __launch_bounds__(256) void k_gemm1(const u16* __restrict__ Ahi,
                                               const u16* __restrict__ Alo,
                                               const u16* __restrict__ WThi,
                                               const u16* __restrict__ WTlo,
                                               const float* __restrict__ bias,
                                               u16* __restrict__ Zout,
                                               float* __restrict__ stats, int M) {
  constexpr int NCB = NC / 128;
  int nxb = (M + 127) >> 7;
  int bid = blockIdx.x;
  int slot = bid & 7;
  int ycb  = (bid >> 3) & (NCB - 1);
  int grp  = bid / (8 * NCB);
  int xb   = grp * 8 + slot;
  if (xb >= nxb) return;
  int brow = xb * 128;
  int bcol = ycb * 128;

  __shared__ u16 AlHi[128 * 32];
  __shared__ u16 AlLo[128 * 32];
  __shared__ u16 BlHi[128 * 32];
  __shared__ u16 BlLo[128 * 32];
  __shared__ float sblk[256];
  int tid = threadIdx.x;
  sblk[tid] = 0.f;
  int lane = tid & 63, wid = tid >> 6;
  int wm = wid & 1, wn = wid >> 1;

  f32x4 zero = {0.f, 0.f, 0.f, 0.f};
  f32x4 acc[4][4];
#pragma unroll
  for (int m = 0; m < 4; m++)
#pragma unroll
    for (int n = 0; n < 4; n++) acc[m][n] = zero;

  int rinc = lane >> 2;
  int cq = (lane & 3) * 8;
  long ra0 = brow + wid * 16 + rinc;  if (ra0 > M - 1) ra0 = M - 1;
  long ra1 = brow + 64 + wid * 16 + rinc; if (ra1 > M - 1) ra1 = M - 1;
  long rb0 = bcol + wid * 16 + rinc;
  long rb1 = bcol + 64 + wid * 16 + rinc;

  const u16* gAh0 = Ahi + ra0 * K + cq;
  const u16* gAh1 = Ahi + ra1 * K + cq;
  const u16* gAl0 = Alo + ra0 * K + cq;
  const u16* gAl1 = Alo + ra1 * K + cq;
  const u16* gBh0 = WThi + rb0 * K + cq;
  const u16* gBh1 = WThi + rb1 * K + cq;
  const u16* gBl0 = WTlo + rb0 * K + cq;
  const u16* gBl1 = WTlo + rb1 * K + cq;
  int lc0 = wid * 512, lc1 = (wid + 4) * 512;

  int fr = lane & 15;
  int kk = (lane >> 4) * 8;
  int fo = (wm * 64 + fr) * 32 + kk;
  int go = (wn * 64 + fr) * 32 + kk;

  const int KS = K / 32;
  for (int kt = 0; kt < KS; ++kt) {
    int k0 = kt * 32;
    gload16(gAh0 + k0, &AlHi[lc0]);
    gload16(gAh1 + k0, &AlHi[lc1]);
    gload16(gAl0 + k0, &AlLo[lc0]);
    gload16(gAl1 + k0, &AlLo[lc1]);
    gload16(gBh0 + k0, &BlHi[lc0]);
    gload16(gBh1 + k0, &BlHi[lc1]);
    gload16(gBl0 + k0, &BlLo[lc0]);
    gload16(gBl1 + k0, &BlLo[lc1]);
    __syncthreads();

    Frag aH[4], bH[4], bL[4], aL[4];
#pragma unroll
    for (int m = 0; m < 4; m++) aH[m].s = *(const s16x8*)(&AlHi[fo + m * 512]);
#pragma unroll
    for (int n = 0; n < 4; n++) bH[n].s = *(const s16x8*)(&BlHi[go + n * 512]);
#pragma unroll
    for (int n = 0; n < 4; n++) bL[n].s = *(const s16x8*)(&BlLo[go + n * 512]);
#pragma unroll
    for (int m = 0; m < 4; m++)
#pragma unroll
      for (int n = 0; n < 4; n++)
        acc[m][n] = __builtin_amdgcn_mfma_f32_16x16x32_bf16(aH[m].b, bH[n].b, acc[m][n], 0, 0, 0);
#pragma unroll
    for (int m = 0; m < 4; m++) aL[m].s = *(const s16x8*)(&AlLo[fo + m * 512]);
#pragma unroll
    for (int m = 0; m < 4; m++)
#pragma unroll
      for (int n = 0; n < 4; n++)
        acc[m][n] = __builtin_amdgcn_mfma_f32_16x16x32_bf16(aL[m].b, bH[n].b, acc[m][n], 0, 0, 0);
#pragma unroll
    for (int m = 0; m < 4; m++)
#pragma unroll
      for (int n = 0; n < 4; n++)
        acc[m][n] = __builtin_amdgcn_mfma_f32_16x16x32_bf16(aH[m].b, bL[n].b, acc[m][n], 0, 0, 0);
    __syncthreads();
  }

  // epilogue: D row=(lane>>4)*4+r, col=lane&15 within each 16x16 frag [m89-verified]
  int colb = bcol + wn * 64;
  float bv[4];
#pragma unroll
  for (int n = 0; n < 4; n++) bv[n] = bias[colb + n * 16 + fr];
  int rb = brow + wm * 64 + ((lane >> 4) << 2);
  float sn[4] = {0.f, 0.f, 0.f, 0.f}, qn[4] = {0.f, 0.f, 0.f, 0.f};
#pragma unroll
  for (int m = 0; m < 4; m++) {
#pragma unroll
    for (int r = 0; r < 4; r++) {
      int row = rb + m * 16 + r;
      if (row < M) {
        size_t base = (size_t)row * NC + colb + fr;
#pragma unroll
        for (int n = 0; n < 4; n++) {
          float z = acc[m][n][r] + bv[n];
          Zout[base + n * 16] = f2bf(z);
          sn[n] += z; qn[n] += z * z;
        }
      }
    }
  }
#pragma unroll
  for (int n = 0; n < 4; n++) {
    sn[n] += __shfl_xor(sn[n], 16); sn[n] += __shfl_xor(sn[n], 32);
    qn[n] += __shfl_xor(qn[n], 16); qn[n] += __shfl_xor(qn[n], 32);
  }
  if (lane < 16) {
#pragma unroll
    for (int n = 0; n < 4; n++) {
      atomicAdd(&sblk[wn * 64 + n * 16 + lane], sn[n]);
      atomicAdd(&sblk[128 + wn * 64 + n * 16 + lane], qn[n]);
    }
  }
  __syncthreads();
  if (tid < 128) atomicAdd(&stats[bcol + tid], sblk[tid]);
  else           atomicAdd(&stats[NC + bcol + (tid - 128)], sblk[tid]);
}

// GEMM2: H2(Mx256) = relu(BN1(Z1))(Mx512) * W2 + b2 via 2 W-segments.
// BN1+ReLU fused into the A reg-staging; sc/sh table computed per block from
// stats1 (bitwise-identical to the old finalize+bn_a2 path). bf16 out + stats2.
__global__ __launch_bounds__(256) void k_gemm2(const u16* __restrict__ Z1,
                                               const u16* __restrict__ WThi,
                                               const u16* __restrict__ WTlo,
                                               const float* __restrict__ bias,
                                               const float* __restrict__ st1,
                                               const float* __restrict__ g1,
                                               const float* __restrict__ be1,
                                               u16* __restrict__ Hout,
                                               float* __restrict__ stats, int M) {
  constexpr int K = EM, NC = DD, NCB = NC / 128;   // 512, 256, 2
  int nxb = (M + 127) >> 7;
  int bid = blockIdx.x;
  int slot = bid & 7;
  int ycb  = (bid >> 3) & (NCB - 1);
  int grp  = bid / (8 * NCB);
  int xb   = grp * 8 + slot;
  if (xb >= nxb) return;
  int brow = xb * 128;
  int bcol = ycb * 128;

  __shared__ u16 AlHi[128 * 32];
  __shared__ u16 BlHi[128 * 32];
  __shared__ u16 BlLo[128 * 32];
  __shared__ float scL[EM];
  __shared__ float shL[EM];
  __shared__ float sblk[256];
  int tid = threadIdx.x;
  sblk[tid] = 0.f;
  // per-block BN1 table from stats (same f32 formula as old k_finalize)
  for (int c = tid; c < EM; c += 256) {
    float mean = st1[c] * RN;
    float var = st1[EM + c] * RN - mean * mean;
    float s = g1[c] * rsqrtf(var + EPS);
    scL[c] = s;
    shL[c] = be1[c] - mean * s;
  }
  int lane = tid & 63, wid = tid >> 6;
  int wm = wid & 1, wn = wid >> 1;

  f32x4 zero = {0.f, 0.f, 0.f, 0.f};
  f32x4 acc[4][4];
#pragma unroll
  for (int m = 0; m < 4; m++)
#pragma unroll
    for (int n = 0; n < 4; n++) acc[m][n] = zero;

  int rinc = lane >> 2;
  int cq = (lane & 3) * 8;
  long ra0 = brow + wid * 16 + rinc;  if (ra0 > M - 1) ra0 = M - 1;
  long ra1 = brow + 64 + wid * 16 + rinc; if (ra1 > M - 1) ra1 = M - 1;
  long rb0 = bcol + wid * 16 + rinc;
  long rb1 = bcol + 64 + wid * 16 + rinc;

  const u16* gZ0 = Z1 + ra0 * K + cq;
  const u16* gZ1 = Z1 + ra1 * K + cq;
  const u16* gBh0 = WThi + rb0 * K + cq;
  const u16* gBh1 = WThi + rb1 * K + cq;
  const u16* gBl0 = WTlo + rb0 * K + cq;
  const u16* gBl1 = WTlo + rb1 * K + cq;
  int lc0 = wid * 512, lc1 = (wid + 4) * 512;

  int fr = lane & 15;
  int kk = (lane >> 4) * 8;
  int fo = (wm * 64 + fr) * 32 + kk;
  int go = (wn * 64 + fr) * 32 + kk;

  __syncthreads();                       // scL/shL ready

  const int KS = K / 32;
  for (int kt = 0; kt < KS; ++kt) {
    int k0 = kt * 32;
    // issue A reg-loads + async W loads first (overlap), then transform
    s16x8 z0 = *(const s16x8*)(gZ0 + k0);
    s16x8 z1 = *(const s16x8*)(gZ1 + k0);
    gload16(gBh0 + k0, &BlHi[lc0]);
    gload16(gBh1 + k0, &BlHi[lc1]);
    gload16(gBl0 + k0, &BlLo[lc0]);
    gload16(gBl1 + k0, &BlLo[lc1]);
    f32x4 s0 = *(const f32x4*)(&scL[k0 + cq]);
    f32x4 s1 = *(const f32x4*)(&scL[k0 + cq + 4]);
    f32x4 h0 = *(const f32x4*)(&shL[k0 + cq]);
    f32x4 h1 = *(const f32x4*)(&shL[k0 + cq + 4]);
    s16x8 o0, o1;
#pragma unroll
    for (int j = 0; j < 4; j++) {
      o0[j]     = (short)f2bf(fmaxf(bf2f((u16)z0[j])     * s0[j] + h0[j], 0.f));
      o0[j + 4] = (short)f2bf(fmaxf(bf2f((u16)z0[j + 4]) * s1[j] + h1[j], 0.f));
      o1[j]     = (short)f2bf(fmaxf(bf2f((u16)z1[j])     * s0[j] + h0[j], 0.f));
      o1[j + 4] = (short)f2bf(fmaxf(bf2f((u16)z1[j + 4]) * s1[j] + h1[j], 0.f));
    }
    *(s16x8*)(&AlHi[lc0 + lane * 8]) = o0;
    *(s16x8*)(&AlHi[lc1 + lane * 8]) = o1;
    __syncthreads();

    Frag aH[4], bH[4], bL[4];
#pragma unroll
    for (int m = 0; m < 4; m++) aH[m].s = *(const s16x8*)(&AlHi[fo + m * 512]);
#pragma unroll
    for (int n = 0; n < 4; n++) bH[n].s = *(const s16x8*)(&BlHi[go + n * 512]);
#pragma unroll
    for (int n = 0; n < 4; n++) bL[n].s = *(const s16x8*)(&BlLo[go + n * 512]);
#pragma unroll
    for (int m = 0; m < 4; m++)
#pragma unroll
      for (int n = 0; n < 4; n++)
        acc[m][n] = __builtin_amdgcn_mfma_f32_16x16x32_bf16(aH[m].b, bH[n].b, acc[m][n], 0, 0, 0);
#pragma unroll
    for (int m = 0; m < 4; m++)
#pragma unroll
      for (int n = 0; n < 4; n++)
        acc[m][n] = __builtin_amdgcn_mfma_f32_16x16x32_bf16(aH[m].b, bL[n].b, acc[m][n], 0, 0, 0);
    __syncthreads();
  }

  int colb = bcol + wn * 64;
  float bv[4];
#pragma unroll
  for (int n = 0; n < 4; n++) bv[n] = bias[colb + n * 16 + fr];
  int rb = brow + wm * 64 + ((lane >> 4) << 2);
  float sn[4] = {0.f, 0.f, 0.f, 0.f}, qn[4] = {0.f, 0.f, 0.f, 0.f};
#pragma unroll
  for (int m = 0; m < 4; m++) {
#pragma unroll
    for (int r = 0; r < 4; r++) {
      int row = rb + m * 16 + r;
      if (row < M) {
        size_t base = (size_t)row * NC + colb + fr;
#pragma unroll
        for (int n = 0; n < 4; n++) {
          float z = acc[m][n][r] + bv[n];
          Hout[base + n * 16] = f2bf(z);
          sn[n] += z; qn[n] += z * z;
        }
      }
    }
  }
#pragma unroll
  for (int n = 0; n < 4; n++) {
    sn[n] += __shfl_xor(sn[n], 16); sn[n] += __shfl_xor(sn[n], 32);
    qn[n] += __shfl_xor(qn[n], 16); qn[n] += __shfl_xor(qn[n], 32);
  }
  if (lane < 16) {
#pragma unroll
    for (int n = 0; n < 4; n++) {
      atomicAdd(&sblk[wn * 64 + n * 16 + lane], sn[n]);
      atomicAdd(&sblk[128 + wn * 64 + n * 16 + lane], qn[n]);
    }
  }
  __syncthreads();
  if (tid < 128) atomicAdd(&stats[bcol + tid], sblk[tid]);
  else           atomicAdd(&stats[NC + bcol + (tid - 128)], sblk[tid]);
}

// final BN2 (no ReLU) on bf16 H2 -> f32 d_out; sc/sh computed inline from stats
__global__ void k_bn_out(const u16* __restrict__ H, const float* __restrict__ st,
                         const float* __restrict__ ga, const float* __restrict__ be,
                         float* __restrict__ out, int n4) {
  int i = blockIdx.x * blockDim.x + threadIdx.x;
  int stride = gridDim.x * blockDim.x;
  for (; i < n4; i += stride) {
    int c = (i * 4) & (DD - 1);
    f32x4 m = *(const f32x4*)(st + c);
    f32x4 q = *(const f32x4*)(st + DD + c);
    f32x4 g = *(const f32x4*)(ga + c);
    f32x4 b = *(const f32x4*)(be + c);
    u16x4 v = *(const u16x4*)(H + (size_t)i * 4);
    f32x4 o;
#pragma unroll
    for (int j = 0; j < 4; j++) {
      float mean = m[j] * RN;
      float var = q[j] * RN - mean * mean;
      float sc = g[j] * rsqrtf(var + EPS);
      float sh = b[j] - mean * sc;
      o[j] = bf2f(v[j]) * sc + sh;
    }
    *(f32x4*)(out + (size_t)i * 4) = o;
  }
}

// ---------------- host ----------------

extern "C" void kernel_launch(void* const* d_in, const int* in_sizes, int n_in,
                              void* d_out, int out_size, void* d_ws, size_t ws_size,
                              hipStream_t stream) {
  const float* x  = (const float*)d_in[0];
  const int* ei   = (const int*)d_in[1];
  const int* esrc = ei;
  const int* edst = ei + NE;
  const float* W1 = (const float*)d_in[2];
  const float* b1 = (const float*)d_in[3];
  const float* g1 = (const float*)d_in[4];
  const float* be1= (const float*)d_in[5];
  const float* W2 = (const float*)d_in[6];
  const float* b2 = (const float*)d_in[7];
  const float* g2 = (const float*)d_in[8];
  const float* be2= (const float*)d_in[9];
  float* out = (float*)d_out;

  char* w = (char*)d_ws;
  auto alloc = [&](size_t bytes) {
    char* p = w;
    w += (bytes + 255) & ~(size_t)255;
    return p;
  };
  // Buffers (total ~136MB; round-1-proven budget was ~138MB):
  //   R0: Z1 bf16 [NN][512]       (GEMM1 out, GEMM2 in)
  //   R1: A1hi|A1lo bf16 [NN][256]x2  (agg out, GEMM1 in)
  //   H2: bf16 [NN][256]          (GEMM2 out, agg/bn_out in; x at l=0)
  char* R0 = alloc((size_t)NN * EM * 2);
  char* R1 = alloc((size_t)NN * EM * 2);
  u16*  H2 = (u16*)alloc((size_t)NN * DD * 2);
  u16* W1hi = (u16*)alloc((size_t)NL * EM * DD * 2);
  u16* W1lo = (u16*)alloc((size_t)NL * EM * DD * 2);
  u16* W2hi = (u16*)alloc((size_t)NL * DD * EM * 2);
  u16* W2lo = (u16*)alloc((size_t)NL * DD * EM * 2);
  // contiguous zero-region: deg | cursor | stats1[NL] | stats2[NL]
  char* zbase = (char*)alloc((size_t)NN * 4);
  int* deg    = (int*)zbase;
  int* cursor = (int*)alloc((size_t)NN * 4);
  float* stats1 = (float*)alloc((size_t)NL * 2 * EM * 4);
  float* stats2 = (float*)alloc((size_t)NL * 2 * DD * 4);
  size_t zspan = (char*)w - zbase;
  int* rowptr = (int*)alloc((size_t)(NN + 1) * 4);
  int* part   = (int*)alloc(64 * 4);
  int* cols   = (int*)alloc((size_t)NE * 4);

  u16* Z1   = (u16*)R0;
  u16* A1hi = (u16*)R1;
  u16* A1lo = (u16*)R1 + (size_t)NN * DD;

  // ---- one-time prep ----
  hipMemsetAsync(zbase, 0, zspan, stream);                // deg+cursor+all stats
  k_deg<<<2048, 256, 0, stream>>>(edst, deg);
  k_scan1<<<SCB, 1024, 0, stream>>>(deg, rowptr, part);
  k_scan2<<<1, 64, 0, stream>>>(part, rowptr);
  k_scan3<<<SCB, 1024, 0, stream>>>(rowptr, part);
  k_fill<<<2048, 256, 0, stream>>>(esrc, edst, rowptr, cursor, cols);
  k_prep_w<<<2048, 256, 0, stream>>>(W1, W1hi, W1lo, DD, EM);
  k_prep_w<<<2048, 256, 0, stream>>>(W2, W2hi, W2lo, EM, DD);
  k_f32_to_bf16<<<2048, 256, 0, stream>>>(x, H2, NN * DD / 8);

  const int NXB = (NN + 127) / 128;                       // 391
  const int G1GRID = ((NXB + 7) / 8) * 8 * (EM / 128);    // 1568
  const int G2GRID = ((NXB + 7) / 8) * 8 * (DD / 128);    // 784

  for (int l = 0; l < NL; ++l) {
    float* st1 = stats1 + (size_t)l * 2 * EM;
    float* st2 = stats2 + (size_t)l * 2 * DD;
    if (l == 0)
      k_agg<false><<<NN / 4, 256, 0, stream>>>(H2, nullptr, nullptr, nullptr,
                                               rowptr, cols, A1hi, A1lo);
    else
      k_agg<true><<<NN / 4, 256, 0, stream>>>(H2, stats2 + (size_t)(l - 1) * 2 * DD,
                                              g2 + (size_t)(l - 1) * DD,
                                              be2 + (size_t)(l - 1) * DD,
                                              rowptr, cols, A1hi, A1lo);

    k_gemm1<DD, EM><<<G1GRID, 256, 0, stream>>>(
        A1hi, A1lo, W1hi + (size_t)l * EM * DD, W1lo + (size_t)l * EM * DD,
        b1 + (size_t)l * EM, Z1, st1, NN);

    k_gemm2<<<G2GRID, 256, 0, stream>>>(
        Z1, W2hi + (size_t)l * DD * EM, W2lo + (size_t)l * DD * EM,
        b2 + (size_t)l * DD, st1, g1 + (size_t)l * EM, be1 + (size_t)l * EM,
        H2, st2, NN);
  }
  k_bn_out<<<2048, 256, 0, stream>>>(H2, stats2 + (size_t)(NL - 1) * 2 * DD,
                                     g2 + (size_t)(NL - 1) * DD,
                                     be2 + (size_t)(NL - 1) * DD,
                                     out, NN * DD / 4);
}